// Round 6
// baseline (1047.207 us; speedup 1.0000x reference)
//
#include <hip/hip_runtime.h>
#include <hip/hip_bf16.h>

#define NN 20000      // nodes
#define NE 640000     // edges
#define DIN 256
#define DM  128

typedef __hip_bfloat16 bf16;
typedef __attribute__((ext_vector_type(8))) short s8;     // 8 bf16 (4 VGPRs) MFMA frag
typedef __attribute__((ext_vector_type(4))) float f4;     // 4 f32 acc

__device__ __forceinline__ float bu2f_lo(unsigned u) { union {unsigned u; float f;} c; c.u = u << 16; return c.f; }
__device__ __forceinline__ float bu2f_hi(unsigned u) { union {unsigned u; float f;} c; c.u = u & 0xffff0000u; return c.f; }
__device__ __forceinline__ unsigned short f2bu(float f) { bf16 t = __float2bfloat16(f); return *reinterpret_cast<unsigned short*>(&t); }
__device__ __forceinline__ unsigned pk2(float lo, float hi) { return (unsigned)f2bu(lo) | ((unsigned)f2bu(hi) << 16); }
__device__ __forceinline__ unsigned addpk(unsigned a, unsigned b) {
    return pk2(bu2f_lo(a) + bu2f_lo(b), bu2f_hi(a) + bu2f_hi(b));
}
__device__ __forceinline__ void up8(uint4 u, float* f) {
    f[0] = bu2f_lo(u.x); f[1] = bu2f_hi(u.x);
    f[2] = bu2f_lo(u.y); f[3] = bu2f_hi(u.y);
    f[4] = bu2f_lo(u.z); f[5] = bu2f_hi(u.z);
    f[6] = bu2f_lo(u.w); f[7] = bu2f_hi(u.w);
}

// ---------------- CSR build (dst-sorted edge list) ----------------
__global__ void hist_k(const int* __restrict__ dst, int* __restrict__ cnt, int E) {
    int e = blockIdx.x * 256 + threadIdx.x;
    if (e < E) atomicAdd(&cnt[dst[e]], 1);
}

__global__ void scan_k(const int* __restrict__ cnt, int* __restrict__ row_ptr, int n) {
    __shared__ int lds[1024];
    __shared__ int carry;
    int t = threadIdx.x;
    if (t == 0) carry = 0;
    __syncthreads();
    for (int base = 0; base < n; base += 1024) {
        int v = (base + t < n) ? cnt[base + t] : 0;
        lds[t] = v;
        __syncthreads();
        for (int off = 1; off < 1024; off <<= 1) {
            int x = (t >= off) ? lds[t - off] : 0;
            __syncthreads();
            lds[t] += x;
            __syncthreads();
        }
        if (base + t < n) row_ptr[base + t] = carry + lds[t] - v;  // exclusive
        __syncthreads();
        if (t == 0) carry += lds[1023];
        __syncthreads();
    }
    if (t == 0) row_ptr[n] = carry;
}

__global__ void scatter_k(const int* __restrict__ src, const int* __restrict__ dst,
                          const int* __restrict__ row_ptr, int* __restrict__ cnt2,
                          int* __restrict__ csr_src, int E) {
    int e = blockIdx.x * 256 + threadIdx.x;
    if (e < E) {
        int d = dst[e];
        int pos = row_ptr[d] + atomicAdd(&cnt2[d], 1);
        csr_src[pos] = src[e];
    }
}

// ---------------- batched f32 -> bf16 convert ----------------
struct Cvt { const float* s[12]; bf16* d[12]; int n[12]; };

__global__ void cvt_many_k(Cvt c) {
    int a = blockIdx.y;
    int n4 = c.n[a] >> 2;                        // all counts divisible by 4
    const float4* s = (const float4*)c.s[a];
    uint2* d = (uint2*)c.d[a];
    for (int i = blockIdx.x * 256 + threadIdx.x; i < n4; i += gridDim.x * 256) {
        float4 v = s[i];
        d[i] = make_uint2(pk2(v.x, v.y), pk2(v.z, v.w));
    }
}

// ---------------- shared GEMM helpers ----------------
// MFMA tile, separate A/W row-bytes. Wave covers rows wr*32+{0..31}, chunk cols
// wc*(NF*16)+{0..NF*16}. Both operands XOR-swizzled 16B slots.
template<int NF, int NKS>
__device__ __forceinline__ void mm2(const char* A, int rbA, const char* W, int rbW,
                                    int wr, int wc, int lr, int lk, f4 (&acc)[2][NF])
{
#pragma unroll
    for (int ks = 0; ks < NKS; ++ks) {
        int w = ks * 64 + (lk << 4);
        s8 af[2], wf[NF];
#pragma unroll
        for (int m = 0; m < 2; ++m) {
            int ar = wr * 32 + m * 16 + lr;
            af[m] = *(const s8*)(A + ar * rbA + (w ^ ((ar & 7) << 4)));
        }
#pragma unroll
        for (int n = 0; n < NF; ++n) {
            int wrow = wc * (NF << 4) + n * 16 + lr;
            wf[n] = *(const s8*)(W + wrow * rbW + (w ^ ((wrow & 7) << 4)));
        }
#pragma unroll
        for (int m = 0; m < 2; ++m)
#pragma unroll
            for (int n = 0; n < NF; ++n)
                acc[m][n] = __builtin_amdgcn_mfma_f32_16x16x32_bf16(af[m], wf[n], acc[m][n], 0, 0, 0);
    }
}

// stage weight tile R rows x KK cols (bf16 row-major, contiguous) into LDS. 512 thr.
template<int R, int KK>
__device__ __forceinline__ void stage_w(char* dst, const bf16* __restrict__ W, int t) {
    constexpr int K8 = KK / 8;
    constexpr int SH = (K8 == 16) ? 4 : 5;
#pragma unroll 2
    for (int f = t; f < R * K8; f += 512) {
        int r = f >> SH, k8 = f & (K8 - 1);
        uint4 wv = *(const uint4*)&W[(size_t)r * KK + (k8 << 3)];
        *(uint4*)(dst + r * (KK * 2) + ((k8 << 4) ^ ((r & 7) << 4))) = wv;
    }
}

// stage a 128-col K-slice (colOff) of a 128x256 row-major matrix into LDS (rowb 256)
__device__ __forceinline__ void stage_w_cols(char* dst, const bf16* __restrict__ W,
                                             int colOff, int t) {
#pragma unroll 2
    for (int f = t; f < 128 * 16; f += 512) {
        int r = f >> 4, k8 = f & 15;
        uint4 wv = *(const uint4*)&W[(size_t)r * 256 + colOff + (k8 << 3)];
        *(uint4*)(dst + r * 256 + ((k8 << 4) ^ ((r & 7) << 4))) = wv;
    }
}

// ---------------- bf16 MFMA GEMM, 64x128 tile (prologue / head) ----------------
// post: 0 none, 1 relu, 2 selu. z selects (W,bias,C) for QKV fusion.
__global__ __launch_bounds__(256, 2)
void gemm_k(const bf16* __restrict__ A, const bf16* __restrict__ A2,
            const bf16* __restrict__ W0, const bf16* __restrict__ W1, const bf16* __restrict__ W2,
            const float* __restrict__ b0, const float* __restrict__ b1, const float* __restrict__ b2,
            float* __restrict__ Cf0,
            bf16* __restrict__ Cb0, bf16* __restrict__ Cb1, bf16* __restrict__ Cb2,
            int N, int K, int M, int post)
{
    __shared__ unsigned short Al[64 * 128];
    __shared__ unsigned short Wl[128 * 128];
    int z = blockIdx.z;
    const bf16* W    = (z == 0) ? W0 : (z == 1 ? W1 : W2);
    const float* bia = (z == 0) ? b0 : (z == 1 ? b1 : b2);
    bf16*  Cb        = (z == 0) ? Cb0 : (z == 1 ? Cb1 : Cb2);
    float* Cf        = (z == 0) ? Cf0 : nullptr;
    int n0 = blockIdx.x * 64, moff = blockIdx.y * 128;
    int t = threadIdx.x;
    int lane = t & 63, wid = t >> 6;
    int wr = wid >> 1, wc = wid & 1;            // wave grid 2x2
    int lr = lane & 15, lk = lane >> 4;

    f4 acc[2][4];
#pragma unroll
    for (int m = 0; m < 2; ++m)
#pragma unroll
        for (int n = 0; n < 4; ++n) acc[m][n] = (f4){0.f, 0.f, 0.f, 0.f};

    const char* Ac = (const char*)Al;
    const char* Wc = (const char*)Wl;

    for (int koff = 0; koff < K; koff += 128) {
        int chunk = (K - koff < 128) ? (K - koff) : 128;   // 64 or 128
        int ksh = (chunk == 64) ? 3 : 4;
        int k8s = 1 << ksh;
        int rowb = chunk * 2;
        for (int f = t; f < (64 << ksh); f += 256) {
            int r = f >> ksh, k8 = f & (k8s - 1);
            int row = n0 + r;
            uint4 av = make_uint4(0, 0, 0, 0);
            if (row < N) {
                av = *(const uint4*)&A[(size_t)row * K + koff + (k8 << 3)];
                if (A2) {
                    uint4 a2 = *(const uint4*)&A2[(size_t)row * K + koff + (k8 << 3)];
                    av.x = addpk(av.x, a2.x); av.y = addpk(av.y, a2.y);
                    av.z = addpk(av.z, a2.z); av.w = addpk(av.w, a2.w);
                }
            }
            *(uint4*)((char*)Al + r * rowb + ((k8 << 4) ^ ((r & 7) << 4))) = av;
        }
        for (int f = t; f < (128 << ksh); f += 256) {
            int r = f >> ksh, k8 = f & (k8s - 1);
            uint4 wv = *(const uint4*)&W[(size_t)(moff + r) * K + koff + (k8 << 3)];
            *(uint4*)((char*)Wl + r * rowb + ((k8 << 4) ^ ((r & 7) << 4))) = wv;
        }
        __syncthreads();
        int nks = chunk >> 5;
        for (int ks = 0; ks < nks; ++ks) {
            int w = ks * 64 + (lk << 4);
            s8 af[2], wf[4];
#pragma unroll
            for (int m = 0; m < 2; ++m) {
                int ar = wr * 32 + m * 16 + lr;
                af[m] = *(const s8*)(Ac + ar * rowb + (w ^ ((ar & 7) << 4)));
            }
#pragma unroll
            for (int n = 0; n < 4; ++n) {
                int wrow = wc * 64 + n * 16 + lr;
                wf[n] = *(const s8*)(Wc + wrow * rowb + (w ^ ((wrow & 7) << 4)));
            }
#pragma unroll
            for (int m = 0; m < 2; ++m)
#pragma unroll
                for (int n = 0; n < 4; ++n)
                    acc[m][n] = __builtin_amdgcn_mfma_f32_16x16x32_bf16(af[m], wf[n], acc[m][n], 0, 0, 0);
        }
        __syncthreads();
    }

    int gcol[4];
#pragma unroll
    for (int n = 0; n < 4; ++n) gcol[n] = moff + wc * 64 + n * 16 + lr;
    float bias_[4];
#pragma unroll
    for (int n = 0; n < 4; ++n) bias_[n] = bia ? bia[gcol[n]] : 0.f;
#pragma unroll
    for (int m = 0; m < 2; ++m)
#pragma unroll
        for (int i = 0; i < 4; ++i) {
            int row = n0 + wr * 32 + m * 16 + lk * 4 + i;
            if (row < N) {
#pragma unroll
                for (int n = 0; n < 4; ++n) {
                    float v = acc[m][n][i] + bias_[n];
                    if (post == 1) v = fmaxf(v, 0.f);
                    else if (post == 2) v = (v > 0.f) ? 1.0507009873554805f * v
                                                      : 1.7580993408473766f * expm1f(v);
                    if (Cf) Cf[(size_t)row * M + gcol[n]] = v;
                    if (Cb) Cb[(size_t)row * M + gcol[n]] = __float2bfloat16(v);
                }
            }
        }
}

// ---------------- mega-fused layer kernel (80 KB LDS -> 2 blocks/CU) ----------------
// Per 64-row block: h2 = LN1(h + (attn+Iw)@Wo^T + bo); ff = relu(h2@Wf1^T+bf1)@Wf2^T+bf2;
// h_new = LN2(h2 + ff) [h2 residual in regs]; optionally QKV for next layer.
// 512 threads = 8 waves (2 row-groups x 4 col-groups).
// LDS 81920 B: smA[0,16K) A_in->h2->h_new (rowb 256) | smW[16K,48K) 32K weight chunk
//            | smF[48K,80K) ffmid (rowb 512) / Wk. LN stats live in phase-dead regions.
__global__ __launch_bounds__(512, 4)
void layer_k(const bf16* __restrict__ attn_b, const bf16* __restrict__ Iw,
             bf16* __restrict__ hres, float* __restrict__ hout_f,
             bf16* __restrict__ Qo, bf16* __restrict__ Ko, bf16* __restrict__ Vo, int doQKV,
             const bf16* __restrict__ Wo, const float* __restrict__ bo,
             const bf16* __restrict__ Wf1, const float* __restrict__ bf1,
             const bf16* __restrict__ Wf2, const float* __restrict__ bf2,
             const bf16* __restrict__ Wq, const float* __restrict__ bqv,
             const bf16* __restrict__ Wk, const float* __restrict__ bkv,
             const bf16* __restrict__ Wv, const float* __restrict__ bvv,
             const float* __restrict__ g1v, const float* __restrict__ b1v,
             const float* __restrict__ g2v, const float* __restrict__ b2v)
{
    extern __shared__ char sm[];
    char* smA = sm;                  // 16K
    char* smW = sm + 16384;          // 32K
    char* smF = sm + 49152;          // 32K
    float* redS1 = (float*)smF;      // LN1 stats: F region unused until GEMM2a
    float* redQ1 = redS1 + 256;
    float* redS2 = (float*)smA;      // LN2 stats: A region dead after GEMM2b
    float* redQ2 = redS2 + 256;

    int n0 = blockIdx.x * 64;
    int t = threadIdx.x;
    int lane = t & 63, wid = t >> 6;
    int wr = wid >> 2, wc = wid & 3;             // 2 x 4 wave grid
    int lr = lane & 15, lk = lane >> 4;
    int gcol[2] = { wc * 32 + lr, wc * 32 + 16 + lr };
    int lrow[2][4];
#pragma unroll
    for (int m = 0; m < 2; ++m)
#pragma unroll
        for (int i = 0; i < 4; ++i) lrow[m][i] = wr * 32 + m * 16 + lk * 4 + i;

    // ---- P1: stage A_in = attn + Iw, Wo ----
    for (int f = t; f < 64 * 16; f += 512) {
        int r = f >> 4, k8 = f & 15;
        int row = n0 + r;
        uint4 av = make_uint4(0, 0, 0, 0);
        if (row < NN) {
            av = *(const uint4*)&attn_b[(size_t)row * DM + (k8 << 3)];
            uint4 a2 = *(const uint4*)&Iw[(size_t)row * DM + (k8 << 3)];
            av.x = addpk(av.x, a2.x); av.y = addpk(av.y, a2.y);
            av.z = addpk(av.z, a2.z); av.w = addpk(av.w, a2.w);
        }
        *(uint4*)(smA + r * 256 + ((k8 << 4) ^ ((r & 7) << 4))) = av;
    }
    stage_w<128, 128>(smW, Wo, t);
    __syncthreads();

    // ---- P2: GEMM1 + bo + h residual + LN1 stats ----
    f4 acc1[2][2];
#pragma unroll
    for (int m = 0; m < 2; ++m) { acc1[m][0] = (f4){0,0,0,0}; acc1[m][1] = (f4){0,0,0,0}; }
    mm2<2, 4>(smA, 256, smW, 256, wr, wc, lr, lk, acc1);
    {
        float b_[2] = { bo[gcol[0]], bo[gcol[1]] };
#pragma unroll
        for (int m = 0; m < 2; ++m)
#pragma unroll
            for (int i = 0; i < 4; ++i) {
                int row = n0 + lrow[m][i];
                bool ok = row < NN;
#pragma unroll
                for (int n = 0; n < 2; ++n) {
                    float r = ok ? __bfloat162float(hres[(size_t)row * DM + gcol[n]]) : 0.f;
                    acc1[m][n][i] += b_[n] + r;
                }
            }
    }
#pragma unroll
    for (int m = 0; m < 2; ++m)
#pragma unroll
        for (int i = 0; i < 4; ++i) {
            float s = acc1[m][0][i] + acc1[m][1][i];
            float q = acc1[m][0][i] * acc1[m][0][i] + acc1[m][1][i] * acc1[m][1][i];
            s += __shfl_xor(s, 1); s += __shfl_xor(s, 2); s += __shfl_xor(s, 4); s += __shfl_xor(s, 8);
            q += __shfl_xor(q, 1); q += __shfl_xor(q, 2); q += __shfl_xor(q, 4); q += __shfl_xor(q, 8);
            if (lr == 0) { redS1[wc * 64 + lrow[m][i]] = s; redQ1[wc * 64 + lrow[m][i]] = q; }
        }
    __syncthreads();

    // ---- P3: LN1 finalize -> h2 to smA; stage Wf1 half 0 ----
    {
        float gam[2] = { g1v[gcol[0]], g1v[gcol[1]] };
        float bet[2] = { b1v[gcol[0]], b1v[gcol[1]] };
#pragma unroll
        for (int m = 0; m < 2; ++m)
#pragma unroll
            for (int i = 0; i < 4; ++i) {
                int lw = lrow[m][i];
                float s = redS1[lw] + redS1[64 + lw] + redS1[128 + lw] + redS1[192 + lw];
                float q = redQ1[lw] + redQ1[64 + lw] + redQ1[128 + lw] + redQ1[192 + lw];
                float mean = s * 0.0078125f;
                float var  = q * 0.0078125f - mean * mean;
                float rstd = rsqrtf(var + 1e-5f);
#pragma unroll
                for (int n = 0; n < 2; ++n)
                    acc1[m][n][i] = (acc1[m][n][i] - mean) * rstd * gam[n] + bet[n];
            }
    }
    // NOTE: h2 writes only touch smA; red reads touch smF -> disjoint, same phase OK
#pragma unroll
    for (int m = 0; m < 2; ++m)
#pragma unroll
        for (int i = 0; i < 4; ++i) {
            int rw = lrow[m][i];
#pragma unroll
            for (int n = 0; n < 2; ++n)
                *(unsigned short*)(smA + rw * 256 + ((gcol[n] * 2) ^ ((rw & 7) << 4))) = f2bu(acc1[m][n][i]);
        }
    stage_w<128, 128>(smW, Wf1, t);
    __syncthreads();

    // ---- P4: GEMM2a -> relu -> ffmid cols 0:128 (overwrites dead LN1 stats) ----
    {
        f4 acc2[2][2];
#pragma unroll
        for (int m = 0; m < 2; ++m) { acc2[m][0] = (f4){0,0,0,0}; acc2[m][1] = (f4){0,0,0,0}; }
        mm2<2, 4>(smA, 256, smW, 256, wr, wc, lr, lk, acc2);
        float b_[2] = { bf1[gcol[0]], bf1[gcol[1]] };
#pragma unroll
        for (int m = 0; m < 2; ++m)
#pragma unroll
            for (int i = 0; i < 4; ++i) {
                int rw = lrow[m][i];
#pragma unroll
                for (int n = 0; n < 2; ++n) {
                    float v = fmaxf(acc2[m][n][i] + b_[n], 0.f);
                    *(unsigned short*)(smF + rw * 512 + ((gcol[n] * 2) ^ ((rw & 7) << 4))) = f2bu(v);
                }
            }
    }
    __syncthreads();

    // ---- P5: stage Wf1 half 1 ----
    stage_w<128, 128>(smW, Wf1 + 128 * 128, t);
    __syncthreads();

    // ---- P6: GEMM2b -> relu -> ffmid cols 128:256 ----
    {
        f4 acc2[2][2];
#pragma unroll
        for (int m = 0; m < 2; ++m) { acc2[m][0] = (f4){0,0,0,0}; acc2[m][1] = (f4){0,0,0,0}; }
        mm2<2, 4>(smA, 256, smW, 256, wr, wc, lr, lk, acc2);
        float b_[2] = { bf1[128 + gcol[0]], bf1[128 + gcol[1]] };
#pragma unroll
        for (int m = 0; m < 2; ++m)
#pragma unroll
            for (int i = 0; i < 4; ++i) {
                int rw = lrow[m][i];
#pragma unroll
                for (int n = 0; n < 2; ++n) {
                    float v = fmaxf(acc2[m][n][i] + b_[n], 0.f);
                    int gc = 256 + gcol[n] * 2;        // (128+gcol)*2
                    *(unsigned short*)(smF + rw * 512 + (gc ^ ((rw & 7) << 4))) = f2bu(v);
                }
            }
    }
    __syncthreads();

    // ---- P7: stage Wf2 K-cols 0:128 ----
    stage_w_cols(smW, Wf2, 0, t);
    __syncthreads();

    // ---- P8: GEMM3a (accumulate) ----
    f4 acc3[2][2];
#pragma unroll
    for (int m = 0; m < 2; ++m) { acc3[m][0] = (f4){0,0,0,0}; acc3[m][1] = (f4){0,0,0,0}; }
    mm2<2, 4>(smF, 512, smW, 256, wr, wc, lr, lk, acc3);
    __syncthreads();

    // ---- P9: stage Wf2 K-cols 128:256 ----
    stage_w_cols(smW, Wf2, 128, t);
    __syncthreads();

    // ---- P10: GEMM3b + bf2 + h2 residual + LN2 stats (A region dead) ----
    mm2<2, 4>(smF + 256, 512, smW, 256, wr, wc, lr, lk, acc3);
    {
        float b_[2] = { bf2[gcol[0]], bf2[gcol[1]] };
#pragma unroll
        for (int m = 0; m < 2; ++m)
#pragma unroll
            for (int i = 0; i < 4; ++i)
#pragma unroll
                for (int n = 0; n < 2; ++n)
                    acc3[m][n][i] += b_[n] + acc1[m][n][i];
    }
#pragma unroll
    for (int m = 0; m < 2; ++m)
#pragma unroll
        for (int i = 0; i < 4; ++i) {
            float s = acc3[m][0][i] + acc3[m][1][i];
            float q = acc3[m][0][i] * acc3[m][0][i] + acc3[m][1][i] * acc3[m][1][i];
            s += __shfl_xor(s, 1); s += __shfl_xor(s, 2); s += __shfl_xor(s, 4); s += __shfl_xor(s, 8);
            q += __shfl_xor(q, 1); q += __shfl_xor(q, 2); q += __shfl_xor(q, 4); q += __shfl_xor(q, 8);
            if (lr == 0) { redS2[wc * 64 + lrow[m][i]] = s; redQ2[wc * 64 + lrow[m][i]] = q; }
        }
    __syncthreads();

    // ---- P11: LN2 finalize; global h stores ----
    {
        float gam[2] = { g2v[gcol[0]], g2v[gcol[1]] };
        float bet[2] = { b2v[gcol[0]], b2v[gcol[1]] };
#pragma unroll
        for (int m = 0; m < 2; ++m)
#pragma unroll
            for (int i = 0; i < 4; ++i) {
                int lw = lrow[m][i];
                float s = redS2[lw] + redS2[64 + lw] + redS2[128 + lw] + redS2[192 + lw];
                float q = redQ2[lw] + redQ2[64 + lw] + redQ2[128 + lw] + redQ2[192 + lw];
                float mean = s * 0.0078125f;
                float var  = q * 0.0078125f - mean * mean;
                float rstd = rsqrtf(var + 1e-5f);
                int row = n0 + lw;
#pragma unroll
                for (int n = 0; n < 2; ++n) {
                    float o = (acc3[m][n][i] - mean) * rstd * gam[n] + bet[n];
                    acc3[m][n][i] = o;
                    if (row < NN) {
                        hres[(size_t)row * DM + gcol[n]] = __float2bfloat16(o);
                        if (hout_f) hout_f[(size_t)row * DM + gcol[n]] = o;
                    }
                }
            }
    }
    if (!doQKV) return;
    __syncthreads();

    // ---- P12: h_new -> smA (overwrites dead LN2 stats); stage Wq ----
#pragma unroll
    for (int m = 0; m < 2; ++m)
#pragma unroll
        for (int i = 0; i < 4; ++i) {
            int rw = lrow[m][i];
#pragma unroll
            for (int n = 0; n < 2; ++n)
                *(unsigned short*)(smA + rw * 256 + ((gcol[n] * 2) ^ ((rw & 7) << 4))) = f2bu(acc3[m][n][i]);
        }
    stage_w<128, 128>(smW, Wq, t);
    __syncthreads();

    // ---- P13: GEMM_Q; stage Wk -> smF (ffmid dead) ----
    {
        f4 aq[2][2];
#pragma unroll
        for (int m = 0; m < 2; ++m) { aq[m][0] = (f4){0,0,0,0}; aq[m][1] = (f4){0,0,0,0}; }
        mm2<2, 4>(smA, 256, smW, 256, wr, wc, lr, lk, aq);
        float b_[2] = { bqv[gcol[0]], bqv[gcol[1]] };
#pragma unroll
        for (int m = 0; m < 2; ++m)
#pragma unroll
            for (int i = 0; i < 4; ++i) {
                int row = n0 + lrow[m][i];
                if (row < NN)
#pragma unroll
                    for (int n = 0; n < 2; ++n)
                        Qo[(size_t)row * DM + gcol[n]] = __float2bfloat16(aq[m][n][i] + b_[n]);
            }
    }
    stage_w<128, 128>(smF, Wk, t);
    __syncthreads();

    // ---- P14: GEMM_K (W in smF); stage Wv -> smW ----
    {
        f4 aq[2][2];
#pragma unroll
        for (int m = 0; m < 2; ++m) { aq[m][0] = (f4){0,0,0,0}; aq[m][1] = (f4){0,0,0,0}; }
        mm2<2, 4>(smA, 256, smF, 256, wr, wc, lr, lk, aq);
        float b_[2] = { bkv[gcol[0]], bkv[gcol[1]] };
#pragma unroll
        for (int m = 0; m < 2; ++m)
#pragma unroll
            for (int i = 0; i < 4; ++i) {
                int row = n0 + lrow[m][i];
                if (row < NN)
#pragma unroll
                    for (int n = 0; n < 2; ++n)
                        Ko[(size_t)row * DM + gcol[n]] = __float2bfloat16(aq[m][n][i] + b_[n]);
            }
    }
    stage_w<128, 128>(smW, Wv, t);
    __syncthreads();

    // ---- P15: GEMM_V ----
    {
        f4 aq[2][2];
#pragma unroll
        for (int m = 0; m < 2; ++m) { aq[m][0] = (f4){0,0,0,0}; aq[m][1] = (f4){0,0,0,0}; }
        mm2<2, 4>(smA, 256, smW, 256, wr, wc, lr, lk, aq);
        float b_[2] = { bvv[gcol[0]], bvv[gcol[1]] };
#pragma unroll
        for (int m = 0; m < 2; ++m)
#pragma unroll
            for (int i = 0; i < 4; ++i) {
                int row = n0 + lrow[m][i];
                if (row < NN)
#pragma unroll
                    for (int n = 0; n < 2; ++n)
                        Vo[(size_t)row * DM + gcol[n]] = __float2bfloat16(aq[m][n][i] + b_[n]);
            }
    }
}

// ---------------- edge attention: one wave per dst, 16 lanes per edge ----------------
__global__ __launch_bounds__(256)
void attn_k(const bf16* __restrict__ Q, const bf16* __restrict__ K,
            const bf16* __restrict__ V, const int* __restrict__ row_ptr,
            const int* __restrict__ csr, bf16* __restrict__ out)
{
    int lane = threadIdx.x & 63;
    int n = blockIdx.x * 4 + (threadIdx.x >> 6);
    int g = lane >> 4, sub = lane & 15;
    const uint4* Q4 = (const uint4*)Q;
    const uint4* K4 = (const uint4*)K;
    const uint4* V4 = (const uint4*)V;
    float q[8];
    up8(Q4[n * 16 + sub], q);
    int e0 = row_ptr[n], e1 = row_ptr[n + 1];
    float acc[8] = {0.f, 0.f, 0.f, 0.f, 0.f, 0.f, 0.f, 0.f};
    float zacc = 0.f;

    int e = e0 + g;
    int s0 = (e < e1) ? csr[e] : 0;
    uint4 k0 = K4[(size_t)s0 * 16 + sub];
    uint4 v0 = V4[(size_t)s0 * 16 + sub];
    for (int base = e0; base < e1; base += 4) {
        int en = base + 4 + g;
        int s1 = (en < e1) ? csr[en] : 0;
        uint4 k1 = K4[(size_t)s1 * 16 + sub];
        uint4 v1 = V4[(size_t)s1 * 16 + sub];
        float kf[8];
        up8(k0, kf);
        float p = q[0] * kf[0] + q[1] * kf[1] + q[2] * kf[2] + q[3] * kf[3]
                + q[4] * kf[4] + q[5] * kf[5] + q[6] * kf[6] + q[7] * kf[7];
        p += __shfl_xor(p, 1);
        float sc = __expf(fminf(fmaxf(p * 0.25f, -10.f), 10.f)) * 0.5f;
        if (base + g >= e1) sc = 0.f;
        float vf[8];
        up8(v0, vf);
#pragma unroll
        for (int j = 0; j < 8; ++j) acc[j] = fmaf(sc, vf[j], acc[j]);
        zacc += sc;
        k0 = k1; v0 = v1;
    }
#pragma unroll
    for (int j = 0; j < 8; ++j) {
        acc[j] += __shfl_xor(acc[j], 16);
        acc[j] += __shfl_xor(acc[j], 32);
    }
    zacc += __shfl_xor(zacc, 16);
    zacc += __shfl_xor(zacc, 32);
    float inv = 1.f / (zacc + 1e-6f);
    if (g == 0) {
        uint4 o;
        o.x = pk2(acc[0] * inv, acc[1] * inv);
        o.y = pk2(acc[2] * inv, acc[3] * inv);
        o.z = pk2(acc[4] * inv, acc[5] * inv);
        o.w = pk2(acc[6] * inv, acc[7] * inv);
        ((uint4*)out)[n * 16 + sub] = o;
    }
}

// ---------------- host side ----------------
static inline void g1(hipStream_t st, const bf16* A, const bf16* A2, const bf16* W,
                      const float* bia, float* Cf, bf16* Cb, int N, int K, int M, int post)
{
    dim3 grid((N + 63) / 64, M / 128, 1);
    gemm_k<<<grid, 256, 0, st>>>(A, A2, W, nullptr, nullptr, bia, nullptr, nullptr,
                                 Cf, Cb, nullptr, nullptr, N, K, M, post);
}

static inline void g3(hipStream_t st, const bf16* A,
                      const bf16* W0, const float* b0, bf16* C0,
                      const bf16* W1, const float* b1, bf16* C1,
                      const bf16* W2, const float* b2, bf16* C2,
                      int N, int K, int M)
{
    dim3 grid((N + 63) / 64, M / 128, 3);
    gemm_k<<<grid, 256, 0, st>>>(A, nullptr, W0, W1, W2, b0, b1, b2,
                                 nullptr, C0, C1, C2, N, K, M, 0);
}

extern "C" void kernel_launch(void* const* d_in, const int* in_sizes, int n_in,
                              void* d_out, int out_size, void* d_ws, size_t ws_size,
                              hipStream_t stream)
{
    const float* x    = (const float*)d_in[0];
    const float* Iin  = (const float*)d_in[1];
    const int*   src  = (const int*)d_in[2];
    const int*   dst  = (const int*)d_in[3];
    const float* Wemb = (const float*)d_in[4];
    const float* Wq   = (const float*)d_in[5];  const float* bq  = (const float*)d_in[6];
    const float* Wk   = (const float*)d_in[7];  const float* bk  = (const float*)d_in[8];
    const float* Wv   = (const float*)d_in[9];  const float* bv  = (const float*)d_in[10];
    const float* Wi   = (const float*)d_in[11]; const float* bi  = (const float*)d_in[12];
    const float* Wo   = (const float*)d_in[13]; const float* bo  = (const float*)d_in[14];
    const float* g1g  = (const float*)d_in[15]; const float* be1 = (const float*)d_in[16];
    const float* g2g  = (const float*)d_in[17]; const float* be2 = (const float*)d_in[18];
    const float* Wf1  = (const float*)d_in[19]; const float* bf1 = (const float*)d_in[20];
    const float* Wf2  = (const float*)d_in[21]; const float* bf2 = (const float*)d_in[22];
    const float* Wm1  = (const float*)d_in[23]; const float* bm1 = (const float*)d_in[24];
    const float* Wm2  = (const float*)d_in[25]; const float* bm2 = (const float*)d_in[26];

    const size_t NF = (size_t)NN * DM;          // 2,560,000
    bf16* B      = (bf16*)d_ws;
    bf16* h_b    = B;                           // bf16 residual stream (in-place updated)
    bf16* Qb     = B + NF;
    bf16* Kb     = B + 2 * NF;
    bf16* Vb     = B + 3 * NF;
    bf16* attn_b = B + 4 * NF;
    bf16* Iw_b   = B + 5 * NF;
    bf16* wts    = B + 6 * NF;
    // weight arena offsets (elements)
    bf16* Wemb_b = wts;                 // 32768
    bf16* Wq_b   = wts + 32768;         // 16384
    bf16* Wk_b   = Wq_b + 16384;
    bf16* Wv_b   = Wk_b + 16384;
    bf16* Wo_b   = Wv_b + 16384;
    bf16* Wi_b   = Wo_b + 16384;        // 8192
    bf16* Wf1_b  = Wi_b + 8192;         // 32768
    bf16* Wf2_b  = Wf1_b + 32768;       // 32768
    bf16* Wm1_b  = Wf2_b + 32768;       // 16384
    bf16* Wm2_b  = Wm1_b + 16384;       // 32768
    bf16* wend   = Wm2_b + 32768;
    // aliases over dead regions
    bf16* x_b    = Qb;                  // N x 256 (spans Qb+Kb), dead before QKV0
    bf16* Iin_b  = Vb;                  // N x 64, dead before QKV0
    bf16* tmp_b  = Qb;                  // head mid (N x 128), QKV dead after last layer
    int* ib      = (int*)wend;
    int* cnt     = ib;
    int* cnt2    = ib + NN;
    int* row_ptr = ib + 2 * NN;
    int* csr     = ib + 3 * NN + 1;

    // ---- CSR build (once per call) ----
    hipMemsetAsync(cnt,  0, NN * sizeof(int), stream);
    hipMemsetAsync(cnt2, 0, NN * sizeof(int), stream);
    hist_k<<<(NE + 255) / 256, 256, 0, stream>>>(dst, cnt, NE);
    scan_k<<<1, 1024, 0, stream>>>(cnt, row_ptr, NN);
    scatter_k<<<(NE + 255) / 256, 256, 0, stream>>>(src, dst, row_ptr, cnt2, csr, NE);

    // ---- batched f32->bf16 conversion of x, I, and all weights ----
    Cvt c;
    c.s[0] = x;    c.d[0] = x_b;    c.n[0] = NN * DIN;
    c.s[1] = Iin;  c.d[1] = Iin_b;  c.n[1] = NN * 64;
    c.s[2] = Wemb; c.d[2] = Wemb_b; c.n[2] = 32768;
    c.s[3] = Wq;   c.d[3] = Wq_b;   c.n[3] = 16384;
    c.s[4] = Wk;   c.d[4] = Wk_b;   c.n[4] = 16384;
    c.s[5] = Wv;   c.d[5] = Wv_b;   c.n[5] = 16384;
    c.s[6] = Wo;   c.d[6] = Wo_b;   c.n[6] = 16384;
    c.s[7] = Wi;   c.d[7] = Wi_b;   c.n[7] = 8192;
    c.s[8] = Wf1;  c.d[8] = Wf1_b;  c.n[8] = 32768;
    c.s[9] = Wf2;  c.d[9] = Wf2_b;  c.n[9] = 32768;
    c.s[10] = Wm1; c.d[10] = Wm1_b; c.n[10] = 16384;
    c.s[11] = Wm2; c.d[11] = Wm2_b; c.n[11] = 32768;
    cvt_many_k<<<dim3(640, 12), 256, 0, stream>>>(c);

    // ---- prologue: embed, Iw, first-layer QKV ----
    g1(stream, x_b,   nullptr, Wemb_b, nullptr, nullptr, h_b, NN, DIN, DM, 0);
    g1(stream, Iin_b, nullptr, Wi_b, bi, nullptr, Iw_b, NN, 64, DM, 0);
    g3(stream, h_b, Wq_b, bq, Qb, Wk_b, bk, Kb, Wv_b, bv, Vb, NN, DM, DM);

    // ---- 10 shared-weight layers: attn + mega-fused ----
    const int nblk = (NN + 63) / 64;
    for (int l = 0; l < 10; ++l) {
        attn_k<<<NN / 4, 256, 0, stream>>>(Qb, Kb, Vb, row_ptr, csr, attn_b);
        layer_k<<<nblk, 512, 81920, stream>>>(
            attn_b, Iw_b, h_b, (l == 9) ? (float*)d_out : nullptr,
            Qb, Kb, Vb, (l < 9) ? 1 : 0,
            Wo_b, bo, Wf1_b, bf1, Wf2_b, bf2,
            Wq_b, bq, Wk_b, bk, Wv_b, bv,
            g1g, be1, g2g, be2);
    }

    // ---- reconstruction head ----
    g1(stream, h_b, nullptr, Wm1_b, bm1, nullptr, tmp_b, NN, DM, DM, 2);   // selu
    float* xhat = (float*)d_out + NF;
    g1(stream, tmp_b, nullptr, Wm2_b, bm2, xhat, nullptr, NN, DM, DIN, 0);
}

// Round 7
// 1030.325 us; speedup vs baseline: 1.0164x; 1.0164x over previous
//
#include <hip/hip_runtime.h>
#include <hip/hip_bf16.h>

#define NN 20000      // nodes
#define NE 640000     // edges
#define DIN 256
#define DM  128

typedef __hip_bfloat16 bf16;
typedef __attribute__((ext_vector_type(8))) short s8;     // 8 bf16 (4 VGPRs) MFMA frag
typedef __attribute__((ext_vector_type(4))) float f4;     // 4 f32 acc

__device__ __forceinline__ float bu2f_lo(unsigned u) { union {unsigned u; float f;} c; c.u = u << 16; return c.f; }
__device__ __forceinline__ float bu2f_hi(unsigned u) { union {unsigned u; float f;} c; c.u = u & 0xffff0000u; return c.f; }
__device__ __forceinline__ unsigned short f2bu(float f) { bf16 t = __float2bfloat16(f); return *reinterpret_cast<unsigned short*>(&t); }
__device__ __forceinline__ unsigned pk2(float lo, float hi) { return (unsigned)f2bu(lo) | ((unsigned)f2bu(hi) << 16); }
__device__ __forceinline__ unsigned addpk(unsigned a, unsigned b) {
    return pk2(bu2f_lo(a) + bu2f_lo(b), bu2f_hi(a) + bu2f_hi(b));
}
__device__ __forceinline__ void up8(uint4 u, float* f) {
    f[0] = bu2f_lo(u.x); f[1] = bu2f_hi(u.x);
    f[2] = bu2f_lo(u.y); f[3] = bu2f_hi(u.y);
    f[4] = bu2f_lo(u.z); f[5] = bu2f_hi(u.z);
    f[6] = bu2f_lo(u.w); f[7] = bu2f_hi(u.w);
}

// ---------------- CSR build (dst-sorted edge list) ----------------
__global__ void hist_k(const int* __restrict__ dst, int* __restrict__ cnt, int E) {
    int e = blockIdx.x * 256 + threadIdx.x;
    if (e < E) atomicAdd(&cnt[dst[e]], 1);
}

__global__ void scan_k(const int* __restrict__ cnt, int* __restrict__ row_ptr, int n) {
    __shared__ int lds[1024];
    __shared__ int carry;
    int t = threadIdx.x;
    if (t == 0) carry = 0;
    __syncthreads();
    for (int base = 0; base < n; base += 1024) {
        int v = (base + t < n) ? cnt[base + t] : 0;
        lds[t] = v;
        __syncthreads();
        for (int off = 1; off < 1024; off <<= 1) {
            int x = (t >= off) ? lds[t - off] : 0;
            __syncthreads();
            lds[t] += x;
            __syncthreads();
        }
        if (base + t < n) row_ptr[base + t] = carry + lds[t] - v;  // exclusive
        __syncthreads();
        if (t == 0) carry += lds[1023];
        __syncthreads();
    }
    if (t == 0) row_ptr[n] = carry;
}

__global__ void scatter_k(const int* __restrict__ src, const int* __restrict__ dst,
                          const int* __restrict__ row_ptr, int* __restrict__ cnt2,
                          int* __restrict__ csr_src, int E) {
    int e = blockIdx.x * 256 + threadIdx.x;
    if (e < E) {
        int d = dst[e];
        int pos = row_ptr[d] + atomicAdd(&cnt2[d], 1);
        csr_src[pos] = src[e];
    }
}

// ---------------- batched f32 -> bf16 convert ----------------
struct Cvt { const float* s[12]; bf16* d[12]; int n[12]; };

__global__ void cvt_many_k(Cvt c) {
    int a = blockIdx.y;
    int n4 = c.n[a] >> 2;                        // all counts divisible by 4
    const float4* s = (const float4*)c.s[a];
    uint2* d = (uint2*)c.d[a];
    for (int i = blockIdx.x * 256 + threadIdx.x; i < n4; i += gridDim.x * 256) {
        float4 v = s[i];
        d[i] = make_uint2(pk2(v.x, v.y), pk2(v.z, v.w));
    }
}

// ---------------- shared GEMM helpers ----------------
// MFMA tile, separate A/W row-bytes. Wave covers rows wr*32+{0..31}, chunk cols
// wc*(NF*16)+{0..NF*16}. Both operands XOR-swizzled 16B slots.
template<int NF, int NKS>
__device__ __forceinline__ void mm2(const char* A, int rbA, const char* W, int rbW,
                                    int wr, int wc, int lr, int lk, f4 (&acc)[2][NF])
{
#pragma unroll
    for (int ks = 0; ks < NKS; ++ks) {
        int w = ks * 64 + (lk << 4);
        s8 af[2], wf[NF];
#pragma unroll
        for (int m = 0; m < 2; ++m) {
            int ar = wr * 32 + m * 16 + lr;
            af[m] = *(const s8*)(A + ar * rbA + (w ^ ((ar & 7) << 4)));
        }
#pragma unroll
        for (int n = 0; n < NF; ++n) {
            int wrow = wc * (NF << 4) + n * 16 + lr;
            wf[n] = *(const s8*)(W + wrow * rbW + (w ^ ((wrow & 7) << 4)));
        }
#pragma unroll
        for (int m = 0; m < 2; ++m)
#pragma unroll
            for (int n = 0; n < NF; ++n)
                acc[m][n] = __builtin_amdgcn_mfma_f32_16x16x32_bf16(af[m], wf[n], acc[m][n], 0, 0, 0);
    }
}

// stage weight tile R rows x KK cols (bf16 row-major, contiguous) into LDS. 512 thr.
template<int R, int KK>
__device__ __forceinline__ void stage_w(char* dst, const bf16* __restrict__ W, int t) {
    constexpr int K8 = KK / 8;
    constexpr int SH = (K8 == 16) ? 4 : 5;
#pragma unroll 2
    for (int f = t; f < R * K8; f += 512) {
        int r = f >> SH, k8 = f & (K8 - 1);
        uint4 wv = *(const uint4*)&W[(size_t)r * KK + (k8 << 3)];
        *(uint4*)(dst + r * (KK * 2) + ((k8 << 4) ^ ((r & 7) << 4))) = wv;
    }
}

// stage a 128-col K-slice (colOff) of a 128x256 row-major matrix into LDS (rowb 256)
__device__ __forceinline__ void stage_w_cols(char* dst, const bf16* __restrict__ W,
                                             int colOff, int t) {
#pragma unroll 2
    for (int f = t; f < 128 * 16; f += 512) {
        int r = f >> 4, k8 = f & 15;
        uint4 wv = *(const uint4*)&W[(size_t)r * 256 + colOff + (k8 << 3)];
        *(uint4*)(dst + r * 256 + ((k8 << 4) ^ ((r & 7) << 4))) = wv;
    }
}

// ---------------- bf16 MFMA GEMM, 64x128 tile (prologue / head) ----------------
// post: 0 none, 1 relu, 2 selu. z selects (W,bias,C) for QKV fusion.
__global__ __launch_bounds__(256, 2)
void gemm_k(const bf16* __restrict__ A, const bf16* __restrict__ A2,
            const bf16* __restrict__ W0, const bf16* __restrict__ W1, const bf16* __restrict__ W2,
            const float* __restrict__ b0, const float* __restrict__ b1, const float* __restrict__ b2,
            float* __restrict__ Cf0,
            bf16* __restrict__ Cb0, bf16* __restrict__ Cb1, bf16* __restrict__ Cb2,
            int N, int K, int M, int post)
{
    __shared__ unsigned short Al[64 * 128];
    __shared__ unsigned short Wl[128 * 128];
    int z = blockIdx.z;
    const bf16* W    = (z == 0) ? W0 : (z == 1 ? W1 : W2);
    const float* bia = (z == 0) ? b0 : (z == 1 ? b1 : b2);
    bf16*  Cb        = (z == 0) ? Cb0 : (z == 1 ? Cb1 : Cb2);
    float* Cf        = (z == 0) ? Cf0 : nullptr;
    int n0 = blockIdx.x * 64, moff = blockIdx.y * 128;
    int t = threadIdx.x;
    int lane = t & 63, wid = t >> 6;
    int wr = wid >> 1, wc = wid & 1;            // wave grid 2x2
    int lr = lane & 15, lk = lane >> 4;

    f4 acc[2][4];
#pragma unroll
    for (int m = 0; m < 2; ++m)
#pragma unroll
        for (int n = 0; n < 4; ++n) acc[m][n] = (f4){0.f, 0.f, 0.f, 0.f};

    const char* Ac = (const char*)Al;
    const char* Wc = (const char*)Wl;

    for (int koff = 0; koff < K; koff += 128) {
        int chunk = (K - koff < 128) ? (K - koff) : 128;   // 64 or 128
        int ksh = (chunk == 64) ? 3 : 4;
        int k8s = 1 << ksh;
        int rowb = chunk * 2;
        for (int f = t; f < (64 << ksh); f += 256) {
            int r = f >> ksh, k8 = f & (k8s - 1);
            int row = n0 + r;
            uint4 av = make_uint4(0, 0, 0, 0);
            if (row < N) {
                av = *(const uint4*)&A[(size_t)row * K + koff + (k8 << 3)];
                if (A2) {
                    uint4 a2 = *(const uint4*)&A2[(size_t)row * K + koff + (k8 << 3)];
                    av.x = addpk(av.x, a2.x); av.y = addpk(av.y, a2.y);
                    av.z = addpk(av.z, a2.z); av.w = addpk(av.w, a2.w);
                }
            }
            *(uint4*)((char*)Al + r * rowb + ((k8 << 4) ^ ((r & 7) << 4))) = av;
        }
        for (int f = t; f < (128 << ksh); f += 256) {
            int r = f >> ksh, k8 = f & (k8s - 1);
            uint4 wv = *(const uint4*)&W[(size_t)(moff + r) * K + koff + (k8 << 3)];
            *(uint4*)((char*)Wl + r * rowb + ((k8 << 4) ^ ((r & 7) << 4))) = wv;
        }
        __syncthreads();
        int nks = chunk >> 5;
        for (int ks = 0; ks < nks; ++ks) {
            int w = ks * 64 + (lk << 4);
            s8 af[2], wf[4];
#pragma unroll
            for (int m = 0; m < 2; ++m) {
                int ar = wr * 32 + m * 16 + lr;
                af[m] = *(const s8*)(Ac + ar * rowb + (w ^ ((ar & 7) << 4)));
            }
#pragma unroll
            for (int n = 0; n < 4; ++n) {
                int wrow = wc * 64 + n * 16 + lr;
                wf[n] = *(const s8*)(Wc + wrow * rowb + (w ^ ((wrow & 7) << 4)));
            }
#pragma unroll
            for (int m = 0; m < 2; ++m)
#pragma unroll
                for (int n = 0; n < 4; ++n)
                    acc[m][n] = __builtin_amdgcn_mfma_f32_16x16x32_bf16(af[m], wf[n], acc[m][n], 0, 0, 0);
        }
        __syncthreads();
    }

    int gcol[4];
#pragma unroll
    for (int n = 0; n < 4; ++n) gcol[n] = moff + wc * 64 + n * 16 + lr;
    float bias_[4];
#pragma unroll
    for (int n = 0; n < 4; ++n) bias_[n] = bia ? bia[gcol[n]] : 0.f;
#pragma unroll
    for (int m = 0; m < 2; ++m)
#pragma unroll
        for (int i = 0; i < 4; ++i) {
            int row = n0 + wr * 32 + m * 16 + lk * 4 + i;
            if (row < N) {
#pragma unroll
                for (int n = 0; n < 4; ++n) {
                    float v = acc[m][n][i] + bias_[n];
                    if (post == 1) v = fmaxf(v, 0.f);
                    else if (post == 2) v = (v > 0.f) ? 1.0507009873554805f * v
                                                      : 1.7580993408473766f * expm1f(v);
                    if (Cf) Cf[(size_t)row * M + gcol[n]] = v;
                    if (Cb) Cb[(size_t)row * M + gcol[n]] = __float2bfloat16(v);
                }
            }
        }
}

// ---------------- mega-fused layer kernel (80 KB LDS -> 2 blocks/CU) ----------------
// Per 64-row block: h2 = LN1(h + (attn+Iw)@Wo^T + bo); ff = relu(h2@Wf1^T+bf1)@Wf2^T+bf2;
// h_new = LN2(h2 + ff) [h2 residual in regs]; optionally QKV for next layer.
// 512 threads = 8 waves (2 row-groups x 4 col-groups).
// LDS 81920 B: smA[0,16K) A_in->h2->h_new (rowb 256) | smW[16K,48K) 32K weight chunk
//            | smF[48K,80K) ffmid (rowb 512) / Wk. LN stats live in phase-dead regions.
// launch_bounds(512,1): compiler picks ~120 VGPR (R5 evidence) <=128 -> 2 blocks/CU
// without spills. (512,4) capped VGPR at 64 and spilled ~35MB/dispatch — R6 regression.
__global__ __launch_bounds__(512, 1)
void layer_k(const bf16* __restrict__ attn_b, const bf16* __restrict__ Iw,
             bf16* __restrict__ hres, float* __restrict__ hout_f,
             bf16* __restrict__ Qo, bf16* __restrict__ Ko, bf16* __restrict__ Vo, int doQKV,
             const bf16* __restrict__ Wo, const float* __restrict__ bo,
             const bf16* __restrict__ Wf1, const float* __restrict__ bf1,
             const bf16* __restrict__ Wf2, const float* __restrict__ bf2,
             const bf16* __restrict__ Wq, const float* __restrict__ bqv,
             const bf16* __restrict__ Wk, const float* __restrict__ bkv,
             const bf16* __restrict__ Wv, const float* __restrict__ bvv,
             const float* __restrict__ g1v, const float* __restrict__ b1v,
             const float* __restrict__ g2v, const float* __restrict__ b2v)
{
    extern __shared__ char sm[];
    char* smA = sm;                  // 16K
    char* smW = sm + 16384;          // 32K
    char* smF = sm + 49152;          // 32K
    float* redS1 = (float*)smF;      // LN1 stats: F region unused until GEMM2a
    float* redQ1 = redS1 + 256;
    float* redS2 = (float*)smA;      // LN2 stats: A region dead after GEMM2b
    float* redQ2 = redS2 + 256;

    int n0 = blockIdx.x * 64;
    int t = threadIdx.x;
    int lane = t & 63, wid = t >> 6;
    int wr = wid >> 2, wc = wid & 3;             // 2 x 4 wave grid
    int lr = lane & 15, lk = lane >> 4;
    int gcol[2] = { wc * 32 + lr, wc * 32 + 16 + lr };
    int lrow[2][4];
#pragma unroll
    for (int m = 0; m < 2; ++m)
#pragma unroll
        for (int i = 0; i < 4; ++i) lrow[m][i] = wr * 32 + m * 16 + lk * 4 + i;

    // ---- P1: stage A_in = attn + Iw, Wo ----
    for (int f = t; f < 64 * 16; f += 512) {
        int r = f >> 4, k8 = f & 15;
        int row = n0 + r;
        uint4 av = make_uint4(0, 0, 0, 0);
        if (row < NN) {
            av = *(const uint4*)&attn_b[(size_t)row * DM + (k8 << 3)];
            uint4 a2 = *(const uint4*)&Iw[(size_t)row * DM + (k8 << 3)];
            av.x = addpk(av.x, a2.x); av.y = addpk(av.y, a2.y);
            av.z = addpk(av.z, a2.z); av.w = addpk(av.w, a2.w);
        }
        *(uint4*)(smA + r * 256 + ((k8 << 4) ^ ((r & 7) << 4))) = av;
    }
    stage_w<128, 128>(smW, Wo, t);
    __syncthreads();

    // ---- P2: GEMM1 + bo + h residual + LN1 stats ----
    f4 acc1[2][2];
#pragma unroll
    for (int m = 0; m < 2; ++m) { acc1[m][0] = (f4){0,0,0,0}; acc1[m][1] = (f4){0,0,0,0}; }
    mm2<2, 4>(smA, 256, smW, 256, wr, wc, lr, lk, acc1);
    {
        float b_[2] = { bo[gcol[0]], bo[gcol[1]] };
#pragma unroll
        for (int m = 0; m < 2; ++m)
#pragma unroll
            for (int i = 0; i < 4; ++i) {
                int row = n0 + lrow[m][i];
                bool ok = row < NN;
#pragma unroll
                for (int n = 0; n < 2; ++n) {
                    float r = ok ? __bfloat162float(hres[(size_t)row * DM + gcol[n]]) : 0.f;
                    acc1[m][n][i] += b_[n] + r;
                }
            }
    }
#pragma unroll
    for (int m = 0; m < 2; ++m)
#pragma unroll
        for (int i = 0; i < 4; ++i) {
            float s = acc1[m][0][i] + acc1[m][1][i];
            float q = acc1[m][0][i] * acc1[m][0][i] + acc1[m][1][i] * acc1[m][1][i];
            s += __shfl_xor(s, 1); s += __shfl_xor(s, 2); s += __shfl_xor(s, 4); s += __shfl_xor(s, 8);
            q += __shfl_xor(q, 1); q += __shfl_xor(q, 2); q += __shfl_xor(q, 4); q += __shfl_xor(q, 8);
            if (lr == 0) { redS1[wc * 64 + lrow[m][i]] = s; redQ1[wc * 64 + lrow[m][i]] = q; }
        }
    __syncthreads();

    // ---- P3: LN1 finalize -> h2 to smA; stage Wf1 half 0 ----
    {
        float gam[2] = { g1v[gcol[0]], g1v[gcol[1]] };
        float bet[2] = { b1v[gcol[0]], b1v[gcol[1]] };
#pragma unroll
        for (int m = 0; m < 2; ++m)
#pragma unroll
            for (int i = 0; i < 4; ++i) {
                int lw = lrow[m][i];
                float s = redS1[lw] + redS1[64 + lw] + redS1[128 + lw] + redS1[192 + lw];
                float q = redQ1[lw] + redQ1[64 + lw] + redQ1[128 + lw] + redQ1[192 + lw];
                float mean = s * 0.0078125f;
                float var  = q * 0.0078125f - mean * mean;
                float rstd = rsqrtf(var + 1e-5f);
#pragma unroll
                for (int n = 0; n < 2; ++n)
                    acc1[m][n][i] = (acc1[m][n][i] - mean) * rstd * gam[n] + bet[n];
            }
    }
    // NOTE: h2 writes only touch smA; red reads touch smF -> disjoint, same phase OK
#pragma unroll
    for (int m = 0; m < 2; ++m)
#pragma unroll
        for (int i = 0; i < 4; ++i) {
            int rw = lrow[m][i];
#pragma unroll
            for (int n = 0; n < 2; ++n)
                *(unsigned short*)(smA + rw * 256 + ((gcol[n] * 2) ^ ((rw & 7) << 4))) = f2bu(acc1[m][n][i]);
        }
    stage_w<128, 128>(smW, Wf1, t);
    __syncthreads();

    // ---- P4: GEMM2a -> relu -> ffmid cols 0:128 (overwrites dead LN1 stats) ----
    {
        f4 acc2[2][2];
#pragma unroll
        for (int m = 0; m < 2; ++m) { acc2[m][0] = (f4){0,0,0,0}; acc2[m][1] = (f4){0,0,0,0}; }
        mm2<2, 4>(smA, 256, smW, 256, wr, wc, lr, lk, acc2);
        float b_[2] = { bf1[gcol[0]], bf1[gcol[1]] };
#pragma unroll
        for (int m = 0; m < 2; ++m)
#pragma unroll
            for (int i = 0; i < 4; ++i) {
                int rw = lrow[m][i];
#pragma unroll
                for (int n = 0; n < 2; ++n) {
                    float v = fmaxf(acc2[m][n][i] + b_[n], 0.f);
                    *(unsigned short*)(smF + rw * 512 + ((gcol[n] * 2) ^ ((rw & 7) << 4))) = f2bu(v);
                }
            }
    }
    __syncthreads();

    // ---- P5: stage Wf1 half 1 ----
    stage_w<128, 128>(smW, Wf1 + 128 * 128, t);
    __syncthreads();

    // ---- P6: GEMM2b -> relu -> ffmid cols 128:256 ----
    {
        f4 acc2[2][2];
#pragma unroll
        for (int m = 0; m < 2; ++m) { acc2[m][0] = (f4){0,0,0,0}; acc2[m][1] = (f4){0,0,0,0}; }
        mm2<2, 4>(smA, 256, smW, 256, wr, wc, lr, lk, acc2);
        float b_[2] = { bf1[128 + gcol[0]], bf1[128 + gcol[1]] };
#pragma unroll
        for (int m = 0; m < 2; ++m)
#pragma unroll
            for (int i = 0; i < 4; ++i) {
                int rw = lrow[m][i];
#pragma unroll
                for (int n = 0; n < 2; ++n) {
                    float v = fmaxf(acc2[m][n][i] + b_[n], 0.f);
                    int gc = 256 + gcol[n] * 2;        // (128+gcol)*2
                    *(unsigned short*)(smF + rw * 512 + (gc ^ ((rw & 7) << 4))) = f2bu(v);
                }
            }
    }
    __syncthreads();

    // ---- P7: stage Wf2 K-cols 0:128 ----
    stage_w_cols(smW, Wf2, 0, t);
    __syncthreads();

    // ---- P8: GEMM3a (accumulate) ----
    f4 acc3[2][2];
#pragma unroll
    for (int m = 0; m < 2; ++m) { acc3[m][0] = (f4){0,0,0,0}; acc3[m][1] = (f4){0,0,0,0}; }
    mm2<2, 4>(smF, 512, smW, 256, wr, wc, lr, lk, acc3);
    __syncthreads();

    // ---- P9: stage Wf2 K-cols 128:256 ----
    stage_w_cols(smW, Wf2, 128, t);
    __syncthreads();

    // ---- P10: GEMM3b + bf2 + h2 residual + LN2 stats (A region dead) ----
    mm2<2, 4>(smF + 256, 512, smW, 256, wr, wc, lr, lk, acc3);
    {
        float b_[2] = { bf2[gcol[0]], bf2[gcol[1]] };
#pragma unroll
        for (int m = 0; m < 2; ++m)
#pragma unroll
            for (int i = 0; i < 4; ++i)
#pragma unroll
                for (int n = 0; n < 2; ++n)
                    acc3[m][n][i] += b_[n] + acc1[m][n][i];
    }
#pragma unroll
    for (int m = 0; m < 2; ++m)
#pragma unroll
        for (int i = 0; i < 4; ++i) {
            float s = acc3[m][0][i] + acc3[m][1][i];
            float q = acc3[m][0][i] * acc3[m][0][i] + acc3[m][1][i] * acc3[m][1][i];
            s += __shfl_xor(s, 1); s += __shfl_xor(s, 2); s += __shfl_xor(s, 4); s += __shfl_xor(s, 8);
            q += __shfl_xor(q, 1); q += __shfl_xor(q, 2); q += __shfl_xor(q, 4); q += __shfl_xor(q, 8);
            if (lr == 0) { redS2[wc * 64 + lrow[m][i]] = s; redQ2[wc * 64 + lrow[m][i]] = q; }
        }
    __syncthreads();

    // ---- P11: LN2 finalize; global h stores ----
    {
        float gam[2] = { g2v[gcol[0]], g2v[gcol[1]] };
        float bet[2] = { b2v[gcol[0]], b2v[gcol[1]] };
#pragma unroll
        for (int m = 0; m < 2; ++m)
#pragma unroll
            for (int i = 0; i < 4; ++i) {
                int lw = lrow[m][i];
                float s = redS2[lw] + redS2[64 + lw] + redS2[128 + lw] + redS2[192 + lw];
                float q = redQ2[lw] + redQ2[64 + lw] + redQ2[128 + lw] + redQ2[192 + lw];
                float mean = s * 0.0078125f;
                float var  = q * 0.0078125f - mean * mean;
                float rstd = rsqrtf(var + 1e-5f);
                int row = n0 + lw;
#pragma unroll
                for (int n = 0; n < 2; ++n) {
                    float o = (acc3[m][n][i] - mean) * rstd * gam[n] + bet[n];
                    acc3[m][n][i] = o;
                    if (row < NN) {
                        hres[(size_t)row * DM + gcol[n]] = __float2bfloat16(o);
                        if (hout_f) hout_f[(size_t)row * DM + gcol[n]] = o;
                    }
                }
            }
    }
    if (!doQKV) return;
    __syncthreads();

    // ---- P12: h_new -> smA (overwrites dead LN2 stats); stage Wq ----
#pragma unroll
    for (int m = 0; m < 2; ++m)
#pragma unroll
        for (int i = 0; i < 4; ++i) {
            int rw = lrow[m][i];
#pragma unroll
            for (int n = 0; n < 2; ++n)
                *(unsigned short*)(smA + rw * 256 + ((gcol[n] * 2) ^ ((rw & 7) << 4))) = f2bu(acc3[m][n][i]);
        }
    stage_w<128, 128>(smW, Wq, t);
    __syncthreads();

    // ---- P13: GEMM_Q; stage Wk -> smF (ffmid dead) ----
    {
        f4 aq[2][2];
#pragma unroll
        for (int m = 0; m < 2; ++m) { aq[m][0] = (f4){0,0,0,0}; aq[m][1] = (f4){0,0,0,0}; }
        mm2<2, 4>(smA, 256, smW, 256, wr, wc, lr, lk, aq);
        float b_[2] = { bqv[gcol[0]], bqv[gcol[1]] };
#pragma unroll
        for (int m = 0; m < 2; ++m)
#pragma unroll
            for (int i = 0; i < 4; ++i) {
                int row = n0 + lrow[m][i];
                if (row < NN)
#pragma unroll
                    for (int n = 0; n < 2; ++n)
                        Qo[(size_t)row * DM + gcol[n]] = __float2bfloat16(aq[m][n][i] + b_[n]);
            }
    }
    stage_w<128, 128>(smF, Wk, t);
    __syncthreads();

    // ---- P14: GEMM_K (W in smF); stage Wv -> smW ----
    {
        f4 aq[2][2];
#pragma unroll
        for (int m = 0; m < 2; ++m) { aq[m][0] = (f4){0,0,0,0}; aq[m][1] = (f4){0,0,0,0}; }
        mm2<2, 4>(smA, 256, smF, 256, wr, wc, lr, lk, aq);
        float b_[2] = { bkv[gcol[0]], bkv[gcol[1]] };
#pragma unroll
        for (int m = 0; m < 2; ++m)
#pragma unroll
            for (int i = 0; i < 4; ++i) {
                int row = n0 + lrow[m][i];
                if (row < NN)
#pragma unroll
                    for (int n = 0; n < 2; ++n)
                        Ko[(size_t)row * DM + gcol[n]] = __float2bfloat16(aq[m][n][i] + b_[n]);
            }
    }
    stage_w<128, 128>(smW, Wv, t);
    __syncthreads();

    // ---- P15: GEMM_V ----
    {
        f4 aq[2][2];
#pragma unroll
        for (int m = 0; m < 2; ++m) { aq[m][0] = (f4){0,0,0,0}; aq[m][1] = (f4){0,0,0,0}; }
        mm2<2, 4>(smA, 256, smW, 256, wr, wc, lr, lk, aq);
        float b_[2] = { bvv[gcol[0]], bvv[gcol[1]] };
#pragma unroll
        for (int m = 0; m < 2; ++m)
#pragma unroll
            for (int i = 0; i < 4; ++i) {
                int row = n0 + lrow[m][i];
                if (row < NN)
#pragma unroll
                    for (int n = 0; n < 2; ++n)
                        Vo[(size_t)row * DM + gcol[n]] = __float2bfloat16(aq[m][n][i] + b_[n]);
            }
    }
}

// ---------------- edge attention: one wave per dst, 16 lanes per edge ----------------
__global__ __launch_bounds__(256)
void attn_k(const bf16* __restrict__ Q, const bf16* __restrict__ K,
            const bf16* __restrict__ V, const int* __restrict__ row_ptr,
            const int* __restrict__ csr, bf16* __restrict__ out)
{
    int lane = threadIdx.x & 63;
    int n = blockIdx.x * 4 + (threadIdx.x >> 6);
    int g = lane >> 4, sub = lane & 15;
    const uint4* Q4 = (const uint4*)Q;
    const uint4* K4 = (const uint4*)K;
    const uint4* V4 = (const uint4*)V;
    float q[8];
    up8(Q4[n * 16 + sub], q);
    int e0 = row_ptr[n], e1 = row_ptr[n + 1];
    float acc[8] = {0.f, 0.f, 0.f, 0.f, 0.f, 0.f, 0.f, 0.f};
    float zacc = 0.f;

    int e = e0 + g;
    int s0 = (e < e1) ? csr[e] : 0;
    uint4 k0 = K4[(size_t)s0 * 16 + sub];
    uint4 v0 = V4[(size_t)s0 * 16 + sub];
    for (int base = e0; base < e1; base += 4) {
        int en = base + 4 + g;
        int s1 = (en < e1) ? csr[en] : 0;
        uint4 k1 = K4[(size_t)s1 * 16 + sub];
        uint4 v1 = V4[(size_t)s1 * 16 + sub];
        float kf[8];
        up8(k0, kf);
        float p = q[0] * kf[0] + q[1] * kf[1] + q[2] * kf[2] + q[3] * kf[3]
                + q[4] * kf[4] + q[5] * kf[5] + q[6] * kf[6] + q[7] * kf[7];
        p += __shfl_xor(p, 1);
        float sc = __expf(fminf(fmaxf(p * 0.25f, -10.f), 10.f)) * 0.5f;
        if (base + g >= e1) sc = 0.f;
        float vf[8];
        up8(v0, vf);
#pragma unroll
        for (int j = 0; j < 8; ++j) acc[j] = fmaf(sc, vf[j], acc[j]);
        zacc += sc;
        k0 = k1; v0 = v1;
    }
#pragma unroll
    for (int j = 0; j < 8; ++j) {
        acc[j] += __shfl_xor(acc[j], 16);
        acc[j] += __shfl_xor(acc[j], 32);
    }
    zacc += __shfl_xor(zacc, 16);
    zacc += __shfl_xor(zacc, 32);
    float inv = 1.f / (zacc + 1e-6f);
    if (g == 0) {
        uint4 o;
        o.x = pk2(acc[0] * inv, acc[1] * inv);
        o.y = pk2(acc[2] * inv, acc[3] * inv);
        o.z = pk2(acc[4] * inv, acc[5] * inv);
        o.w = pk2(acc[6] * inv, acc[7] * inv);
        ((uint4*)out)[n * 16 + sub] = o;
    }
}

// ---------------- host side ----------------
static inline void g1(hipStream_t st, const bf16* A, const bf16* A2, const bf16* W,
                      const float* bia, float* Cf, bf16* Cb, int N, int K, int M, int post)
{
    dim3 grid((N + 63) / 64, M / 128, 1);
    gemm_k<<<grid, 256, 0, st>>>(A, A2, W, nullptr, nullptr, bia, nullptr, nullptr,
                                 Cf, Cb, nullptr, nullptr, N, K, M, post);
}

static inline void g3(hipStream_t st, const bf16* A,
                      const bf16* W0, const float* b0, bf16* C0,
                      const bf16* W1, const float* b1, bf16* C1,
                      const bf16* W2, const float* b2, bf16* C2,
                      int N, int K, int M)
{
    dim3 grid((N + 63) / 64, M / 128, 3);
    gemm_k<<<grid, 256, 0, st>>>(A, nullptr, W0, W1, W2, b0, b1, b2,
                                 nullptr, C0, C1, C2, N, K, M, 0);
}

extern "C" void kernel_launch(void* const* d_in, const int* in_sizes, int n_in,
                              void* d_out, int out_size, void* d_ws, size_t ws_size,
                              hipStream_t stream)
{
    const float* x    = (const float*)d_in[0];
    const float* Iin  = (const float*)d_in[1];
    const int*   src  = (const int*)d_in[2];
    const int*   dst  = (const int*)d_in[3];
    const float* Wemb = (const float*)d_in[4];
    const float* Wq   = (const float*)d_in[5];  const float* bq  = (const float*)d_in[6];
    const float* Wk   = (const float*)d_in[7];  const float* bk  = (const float*)d_in[8];
    const float* Wv   = (const float*)d_in[9];  const float* bv  = (const float*)d_in[10];
    const float* Wi   = (const float*)d_in[11]; const float* bi  = (const float*)d_in[12];
    const float* Wo   = (const float*)d_in[13]; const float* bo  = (const float*)d_in[14];
    const float* g1g  = (const float*)d_in[15]; const float* be1 = (const float*)d_in[16];
    const float* g2g  = (const float*)d_in[17]; const float* be2 = (const float*)d_in[18];
    const float* Wf1  = (const float*)d_in[19]; const float* bf1 = (const float*)d_in[20];
    const float* Wf2  = (const float*)d_in[21]; const float* bf2 = (const float*)d_in[22];
    const float* Wm1  = (const float*)d_in[23]; const float* bm1 = (const float*)d_in[24];
    const float* Wm2  = (const float*)d_in[25]; const float* bm2 = (const float*)d_in[26];

    const size_t NF = (size_t)NN * DM;          // 2,560,000
    bf16* B      = (bf16*)d_ws;
    bf16* h_b    = B;                           // bf16 residual stream (in-place updated)
    bf16* Qb     = B + NF;
    bf16* Kb     = B + 2 * NF;
    bf16* Vb     = B + 3 * NF;
    bf16* attn_b = B + 4 * NF;
    bf16* Iw_b   = B + 5 * NF;
    bf16* wts    = B + 6 * NF;
    // weight arena offsets (elements)
    bf16* Wemb_b = wts;                 // 32768
    bf16* Wq_b   = wts + 32768;         // 16384
    bf16* Wk_b   = Wq_b + 16384;
    bf16* Wv_b   = Wk_b + 16384;
    bf16* Wo_b   = Wv_b + 16384;
    bf16* Wi_b   = Wo_b + 16384;        // 8192
    bf16* Wf1_b  = Wi_b + 8192;         // 32768
    bf16* Wf2_b  = Wf1_b + 32768;       // 32768
    bf16* Wm1_b  = Wf2_b + 32768;       // 16384
    bf16* Wm2_b  = Wm1_b + 16384;       // 32768
    bf16* wend   = Wm2_b + 32768;
    // aliases over dead regions
    bf16* x_b    = Qb;                  // N x 256 (spans Qb+Kb), dead before QKV0
    bf16* Iin_b  = Vb;                  // N x 64, dead before QKV0
    bf16* tmp_b  = Qb;                  // head mid (N x 128), QKV dead after last layer
    int* ib      = (int*)wend;
    int* cnt     = ib;
    int* cnt2    = ib + NN;
    int* row_ptr = ib + 2 * NN;
    int* csr     = ib + 3 * NN + 1;

    // ---- CSR build (once per call) ----
    hipMemsetAsync(cnt,  0, NN * sizeof(int), stream);
    hipMemsetAsync(cnt2, 0, NN * sizeof(int), stream);
    hist_k<<<(NE + 255) / 256, 256, 0, stream>>>(dst, cnt, NE);
    scan_k<<<1, 1024, 0, stream>>>(cnt, row_ptr, NN);
    scatter_k<<<(NE + 255) / 256, 256, 0, stream>>>(src, dst, row_ptr, cnt2, csr, NE);

    // ---- batched f32->bf16 conversion of x, I, and all weights ----
    Cvt c;
    c.s[0] = x;    c.d[0] = x_b;    c.n[0] = NN * DIN;
    c.s[1] = Iin;  c.d[1] = Iin_b;  c.n[1] = NN * 64;
    c.s[2] = Wemb; c.d[2] = Wemb_b; c.n[2] = 32768;
    c.s[3] = Wq;   c.d[3] = Wq_b;   c.n[3] = 16384;
    c.s[4] = Wk;   c.d[4] = Wk_b;   c.n[4] = 16384;
    c.s[5] = Wv;   c.d[5] = Wv_b;   c.n[5] = 16384;
    c.s[6] = Wo;   c.d[6] = Wo_b;   c.n[6] = 16384;
    c.s[7] = Wi;   c.d[7] = Wi_b;   c.n[7] = 8192;
    c.s[8] = Wf1;  c.d[8] = Wf1_b;  c.n[8] = 32768;
    c.s[9] = Wf2;  c.d[9] = Wf2_b;  c.n[9] = 32768;
    c.s[10] = Wm1; c.d[10] = Wm1_b; c.n[10] = 16384;
    c.s[11] = Wm2; c.d[11] = Wm2_b; c.n[11] = 32768;
    cvt_many_k<<<dim3(640, 12), 256, 0, stream>>>(c);

    // ---- prologue: embed, Iw, first-layer QKV ----
    g1(stream, x_b,   nullptr, Wemb_b, nullptr, nullptr, h_b, NN, DIN, DM, 0);
    g1(stream, Iin_b, nullptr, Wi_b, bi, nullptr, Iw_b, NN, 64, DM, 0);
    g3(stream, h_b, Wq_b, bq, Qb, Wk_b, bk, Kb, Wv_b, bv, Vb, NN, DM, DM);

    // ---- 10 shared-weight layers: attn + mega-fused ----
    const int nblk = (NN + 63) / 64;
    for (int l = 0; l < 10; ++l) {
        attn_k<<<NN / 4, 256, 0, stream>>>(Qb, Kb, Vb, row_ptr, csr, attn_b);
        layer_k<<<nblk, 512, 81920, stream>>>(
            attn_b, Iw_b, h_b, (l == 9) ? (float*)d_out : nullptr,
            Qb, Kb, Vb, (l < 9) ? 1 : 0,
            Wo_b, bo, Wf1_b, bf1, Wf2_b, bf2,
            Wq_b, bq, Wk_b, bk, Wv_b, bv,
            g1g, be1, g2g, be2);
    }

    // ---- reconstruction head ----
    g1(stream, h_b, nullptr, Wm1_b, bm1, nullptr, tmp_b, NN, DM, DM, 2);   // selu
    float* xhat = (float*)d_out + NF;
    g1(stream, tmp_b, nullptr, Wm2_b, bm2, xhat, nullptr, NN, DM, DIN, 0);
}

// Round 8
// 900.439 us; speedup vs baseline: 1.1630x; 1.1442x over previous
//
#include <hip/hip_runtime.h>
#include <hip/hip_bf16.h>

#define NN 20000      // nodes
#define NE 640000     // edges
#define DIN 256
#define DM  128
#define ROWS 96       // rows per layer_k block (209 blocks -> single scheduling round)

typedef __hip_bfloat16 bf16;
typedef __attribute__((ext_vector_type(8))) short s8;     // 8 bf16 (4 VGPRs) MFMA frag
typedef __attribute__((ext_vector_type(4))) float f4;     // 4 f32 acc

__device__ __forceinline__ float bu2f_lo(unsigned u) { union {unsigned u; float f;} c; c.u = u << 16; return c.f; }
__device__ __forceinline__ float bu2f_hi(unsigned u) { union {unsigned u; float f;} c; c.u = u & 0xffff0000u; return c.f; }
__device__ __forceinline__ unsigned short f2bu(float f) { bf16 t = __float2bfloat16(f); return *reinterpret_cast<unsigned short*>(&t); }
__device__ __forceinline__ unsigned pk2(float lo, float hi) { return (unsigned)f2bu(lo) | ((unsigned)f2bu(hi) << 16); }
__device__ __forceinline__ unsigned addpk(unsigned a, unsigned b) {
    return pk2(bu2f_lo(a) + bu2f_lo(b), bu2f_hi(a) + bu2f_hi(b));
}
__device__ __forceinline__ void up8(uint4 u, float* f) {
    f[0] = bu2f_lo(u.x); f[1] = bu2f_hi(u.x);
    f[2] = bu2f_lo(u.y); f[3] = bu2f_hi(u.y);
    f[4] = bu2f_lo(u.z); f[5] = bu2f_hi(u.z);
    f[6] = bu2f_lo(u.w); f[7] = bu2f_hi(u.w);
}

// ---------------- CSR build (dst-sorted edge list) ----------------
__global__ void hist_k(const int* __restrict__ dst, int* __restrict__ cnt, int E) {
    int e = blockIdx.x * 256 + threadIdx.x;
    if (e < E) atomicAdd(&cnt[dst[e]], 1);
}

__global__ void scan_k(const int* __restrict__ cnt, int* __restrict__ row_ptr, int n) {
    __shared__ int lds[1024];
    __shared__ int carry;
    int t = threadIdx.x;
    if (t == 0) carry = 0;
    __syncthreads();
    for (int base = 0; base < n; base += 1024) {
        int v = (base + t < n) ? cnt[base + t] : 0;
        lds[t] = v;
        __syncthreads();
        for (int off = 1; off < 1024; off <<= 1) {
            int x = (t >= off) ? lds[t - off] : 0;
            __syncthreads();
            lds[t] += x;
            __syncthreads();
        }
        if (base + t < n) row_ptr[base + t] = carry + lds[t] - v;  // exclusive
        __syncthreads();
        if (t == 0) carry += lds[1023];
        __syncthreads();
    }
    if (t == 0) row_ptr[n] = carry;
}

__global__ void scatter_k(const int* __restrict__ src, const int* __restrict__ dst,
                          const int* __restrict__ row_ptr, int* __restrict__ cnt2,
                          int* __restrict__ csr_src, int E) {
    int e = blockIdx.x * 256 + threadIdx.x;
    if (e < E) {
        int d = dst[e];
        int pos = row_ptr[d] + atomicAdd(&cnt2[d], 1);
        csr_src[pos] = src[e];
    }
}

// ---------------- batched f32 -> bf16 convert ----------------
struct Cvt { const float* s[12]; bf16* d[12]; int n[12]; };

__global__ void cvt_many_k(Cvt c) {
    int a = blockIdx.y;
    int n4 = c.n[a] >> 2;                        // all counts divisible by 4
    const float4* s = (const float4*)c.s[a];
    uint2* d = (uint2*)c.d[a];
    for (int i = blockIdx.x * 256 + threadIdx.x; i < n4; i += gridDim.x * 256) {
        float4 v = s[i];
        d[i] = make_uint2(pk2(v.x, v.y), pk2(v.z, v.w));
    }
}

// ---------------- shared GEMM helpers ----------------
// MFMA tile: wave covers MR*16 rows at wr*(MR*16), NF*16 cols at wc*(NF*16).
// A,W in LDS, XOR-swizzled 16B slots, separate row-bytes.
template<int MR, int NF, int NKS>
__device__ __forceinline__ void mm2(const char* A, int rbA, const char* W, int rbW,
                                    int wr, int wc, int lr, int lk, f4 (&acc)[MR][NF])
{
#pragma unroll
    for (int ks = 0; ks < NKS; ++ks) {
        int w = ks * 64 + (lk << 4);
        s8 af[MR], wf[NF];
#pragma unroll
        for (int m = 0; m < MR; ++m) {
            int ar = wr * (MR * 16) + m * 16 + lr;
            af[m] = *(const s8*)(A + ar * rbA + (w ^ ((ar & 7) << 4)));
        }
#pragma unroll
        for (int n = 0; n < NF; ++n) {
            int wrow = wc * (NF << 4) + n * 16 + lr;
            wf[n] = *(const s8*)(W + wrow * rbW + (w ^ ((wrow & 7) << 4)));
        }
#pragma unroll
        for (int m = 0; m < MR; ++m)
#pragma unroll
            for (int n = 0; n < NF; ++n)
                acc[m][n] = __builtin_amdgcn_mfma_f32_16x16x32_bf16(af[m], wf[n], acc[m][n], 0, 0, 0);
    }
}

// stage weight tile R rows x KK cols (bf16 row-major, contiguous) into LDS. 512 thr.
template<int R, int KK>
__device__ __forceinline__ void stage_w(char* dst, const bf16* __restrict__ W, int t) {
    constexpr int K8 = KK / 8;
    constexpr int SH = (K8 == 16) ? 4 : 5;
#pragma unroll 2
    for (int f = t; f < R * K8; f += 512) {
        int r = f >> SH, k8 = f & (K8 - 1);
        uint4 wv = *(const uint4*)&W[(size_t)r * KK + (k8 << 3)];
        *(uint4*)(dst + r * (KK * 2) + ((k8 << 4) ^ ((r & 7) << 4))) = wv;
    }
}

// ---------------- bf16 MFMA GEMM, 64x128 tile (prologue / head) ----------------
// post: 0 none, 1 relu, 2 selu. z selects (W,bias,C) for QKV fusion.
__global__ __launch_bounds__(256, 2)
void gemm_k(const bf16* __restrict__ A, const bf16* __restrict__ A2,
            const bf16* __restrict__ W0, const bf16* __restrict__ W1, const bf16* __restrict__ W2,
            const float* __restrict__ b0, const float* __restrict__ b1, const float* __restrict__ b2,
            float* __restrict__ Cf0,
            bf16* __restrict__ Cb0, bf16* __restrict__ Cb1, bf16* __restrict__ Cb2,
            int N, int K, int M, int post)
{
    __shared__ unsigned short Al[64 * 128];
    __shared__ unsigned short Wl[128 * 128];
    int z = blockIdx.z;
    const bf16* W    = (z == 0) ? W0 : (z == 1 ? W1 : W2);
    const float* bia = (z == 0) ? b0 : (z == 1 ? b1 : b2);
    bf16*  Cb        = (z == 0) ? Cb0 : (z == 1 ? Cb1 : Cb2);
    float* Cf        = (z == 0) ? Cf0 : nullptr;
    int n0 = blockIdx.x * 64, moff = blockIdx.y * 128;
    int t = threadIdx.x;
    int lane = t & 63, wid = t >> 6;
    int wr = wid >> 1, wc = wid & 1;            // wave grid 2x2
    int lr = lane & 15, lk = lane >> 4;

    f4 acc[2][4];
#pragma unroll
    for (int m = 0; m < 2; ++m)
#pragma unroll
        for (int n = 0; n < 4; ++n) acc[m][n] = (f4){0.f, 0.f, 0.f, 0.f};

    const char* Ac = (const char*)Al;
    const char* Wc = (const char*)Wl;

    for (int koff = 0; koff < K; koff += 128) {
        int chunk = (K - koff < 128) ? (K - koff) : 128;   // 64 or 128
        int ksh = (chunk == 64) ? 3 : 4;
        int k8s = 1 << ksh;
        int rowb = chunk * 2;
        for (int f = t; f < (64 << ksh); f += 256) {
            int r = f >> ksh, k8 = f & (k8s - 1);
            int row = n0 + r;
            uint4 av = make_uint4(0, 0, 0, 0);
            if (row < N) {
                av = *(const uint4*)&A[(size_t)row * K + koff + (k8 << 3)];
                if (A2) {
                    uint4 a2 = *(const uint4*)&A2[(size_t)row * K + koff + (k8 << 3)];
                    av.x = addpk(av.x, a2.x); av.y = addpk(av.y, a2.y);
                    av.z = addpk(av.z, a2.z); av.w = addpk(av.w, a2.w);
                }
            }
            *(uint4*)((char*)Al + r * rowb + ((k8 << 4) ^ ((r & 7) << 4))) = av;
        }
        for (int f = t; f < (128 << ksh); f += 256) {
            int r = f >> ksh, k8 = f & (k8s - 1);
            uint4 wv = *(const uint4*)&W[(size_t)(moff + r) * K + koff + (k8 << 3)];
            *(uint4*)((char*)Wl + r * rowb + ((k8 << 4) ^ ((r & 7) << 4))) = wv;
        }
        __syncthreads();
        int nks = chunk >> 5;
        for (int ks = 0; ks < nks; ++ks) {
            int w = ks * 64 + (lk << 4);
            s8 af[2], wf[4];
#pragma unroll
            for (int m = 0; m < 2; ++m) {
                int ar = wr * 32 + m * 16 + lr;
                af[m] = *(const s8*)(Ac + ar * rowb + (w ^ ((ar & 7) << 4)));
            }
#pragma unroll
            for (int n = 0; n < 4; ++n) {
                int wrow = wc * 64 + n * 16 + lr;
                wf[n] = *(const s8*)(Wc + wrow * rowb + (w ^ ((wrow & 7) << 4)));
            }
#pragma unroll
            for (int m = 0; m < 2; ++m)
#pragma unroll
                for (int n = 0; n < 4; ++n)
                    acc[m][n] = __builtin_amdgcn_mfma_f32_16x16x32_bf16(af[m], wf[n], acc[m][n], 0, 0, 0);
        }
        __syncthreads();
    }

    int gcol[4];
#pragma unroll
    for (int n = 0; n < 4; ++n) gcol[n] = moff + wc * 64 + n * 16 + lr;
    float bias_[4];
#pragma unroll
    for (int n = 0; n < 4; ++n) bias_[n] = bia ? bia[gcol[n]] : 0.f;
#pragma unroll
    for (int m = 0; m < 2; ++m)
#pragma unroll
        for (int i = 0; i < 4; ++i) {
            int row = n0 + wr * 32 + m * 16 + lk * 4 + i;
            if (row < N) {
#pragma unroll
                for (int n = 0; n < 4; ++n) {
                    float v = acc[m][n][i] + bias_[n];
                    if (post == 1) v = fmaxf(v, 0.f);
                    else if (post == 2) v = (v > 0.f) ? 1.0507009873554805f * v
                                                      : 1.7580993408473766f * expm1f(v);
                    if (Cf) Cf[(size_t)row * M + gcol[n]] = v;
                    if (Cb) Cb[(size_t)row * M + gcol[n]] = __float2bfloat16(v);
                }
            }
        }
}

// ---------------- mega-fused layer kernel (96 rows/block, 136 KB LDS) ----------------
// grid = ceil(N/96) = 209 <= 256 CUs -> SINGLE block-round; chain latency paid once.
// Wf1/Wf2 staged WHOLE (64K smW) -> 11 barriers (was 15). 1 block/CU accepted.
// 512 threads = 8 waves (2 row-groups x 48 rows, 4 col-groups).
// LDS 139264 B: smA[0,24K) A_in->h2->h_new (rowb 256) | smW[24K,88K) 64K weights
//             | smF[88K,136K) ffmid 96x256 (rowb 512) / Wk. LN stats in dead regions.
__global__ __launch_bounds__(512, 1)
void layer_k(const bf16* __restrict__ attn_b, const bf16* __restrict__ Iw,
             bf16* __restrict__ hres, float* __restrict__ hout_f,
             bf16* __restrict__ Qo, bf16* __restrict__ Ko, bf16* __restrict__ Vo, int doQKV,
             const bf16* __restrict__ Wo, const float* __restrict__ bo,
             const bf16* __restrict__ Wf1, const float* __restrict__ bf1,
             const bf16* __restrict__ Wf2, const float* __restrict__ bf2,
             const bf16* __restrict__ Wq, const float* __restrict__ bqv,
             const bf16* __restrict__ Wk, const float* __restrict__ bkv,
             const bf16* __restrict__ Wv, const float* __restrict__ bvv,
             const float* __restrict__ g1v, const float* __restrict__ b1v,
             const float* __restrict__ g2v, const float* __restrict__ b2v)
{
    extern __shared__ char sm[];
    char* smA = sm;                  // 24K  (96 rows x 256 B)
    char* smW = sm + 24576;          // 64K
    char* smF = sm + 90112;          // 48K  (96 rows x 512 B)
    float* redS1 = (float*)smF;      // LN1 stats (4 wc-groups x 96): F dead until P4
    float* redQ1 = redS1 + 384;
    float* redS2 = (float*)smA;      // LN2 stats: A dead after GEMM2 (P4)
    float* redQ2 = redS2 + 384;

    int n0 = blockIdx.x * ROWS;
    int t = threadIdx.x;
    int lane = t & 63, wid = t >> 6;
    int wr = wid >> 2, wc = wid & 3;             // 2 x 4 wave grid
    int lr = lane & 15, lk = lane >> 4;
    int gcol[2] = { wc * 32 + lr, wc * 32 + 16 + lr };
    int lrow[3][4];
#pragma unroll
    for (int m = 0; m < 3; ++m)
#pragma unroll
        for (int i = 0; i < 4; ++i) lrow[m][i] = wr * 48 + m * 16 + lk * 4 + i;

    // ---- P1: stage A_in = attn + Iw -> smA; Wo -> smW ----
    for (int f = t; f < ROWS * 16; f += 512) {
        int r = f >> 4, k8 = f & 15;
        int row = n0 + r;
        uint4 av = make_uint4(0, 0, 0, 0);
        if (row < NN) {
            av = *(const uint4*)&attn_b[(size_t)row * DM + (k8 << 3)];
            uint4 a2 = *(const uint4*)&Iw[(size_t)row * DM + (k8 << 3)];
            av.x = addpk(av.x, a2.x); av.y = addpk(av.y, a2.y);
            av.z = addpk(av.z, a2.z); av.w = addpk(av.w, a2.w);
        }
        *(uint4*)(smA + r * 256 + ((k8 << 4) ^ ((r & 7) << 4))) = av;
    }
    stage_w<128, 128>(smW, Wo, t);
    __syncthreads();                                           // B1

    // ---- P2: GEMM1 + bo + h residual + LN1 stats ----
    f4 acc1[3][2];
#pragma unroll
    for (int m = 0; m < 3; ++m) { acc1[m][0] = (f4){0,0,0,0}; acc1[m][1] = (f4){0,0,0,0}; }
    mm2<3, 2, 4>(smA, 256, smW, 256, wr, wc, lr, lk, acc1);
    {
        float b_[2] = { bo[gcol[0]], bo[gcol[1]] };
#pragma unroll
        for (int m = 0; m < 3; ++m)
#pragma unroll
            for (int i = 0; i < 4; ++i) {
                int row = n0 + lrow[m][i];
                bool ok = row < NN;
#pragma unroll
                for (int n = 0; n < 2; ++n) {
                    float r = ok ? __bfloat162float(hres[(size_t)row * DM + gcol[n]]) : 0.f;
                    acc1[m][n][i] += b_[n] + r;
                }
            }
    }
#pragma unroll
    for (int m = 0; m < 3; ++m)
#pragma unroll
        for (int i = 0; i < 4; ++i) {
            float s = acc1[m][0][i] + acc1[m][1][i];
            float q = acc1[m][0][i] * acc1[m][0][i] + acc1[m][1][i] * acc1[m][1][i];
            s += __shfl_xor(s, 1); s += __shfl_xor(s, 2); s += __shfl_xor(s, 4); s += __shfl_xor(s, 8);
            q += __shfl_xor(q, 1); q += __shfl_xor(q, 2); q += __shfl_xor(q, 4); q += __shfl_xor(q, 8);
            if (lr == 0) { redS1[wc * ROWS + lrow[m][i]] = s; redQ1[wc * ROWS + lrow[m][i]] = q; }
        }
    __syncthreads();                                           // B2

    // ---- P3: LN1 finalize -> h2 to smA; stage Wf1 WHOLE (64K) ----
    {
        float gam[2] = { g1v[gcol[0]], g1v[gcol[1]] };
        float bet[2] = { b1v[gcol[0]], b1v[gcol[1]] };
#pragma unroll
        for (int m = 0; m < 3; ++m)
#pragma unroll
            for (int i = 0; i < 4; ++i) {
                int lw = lrow[m][i];
                float s = redS1[lw] + redS1[ROWS + lw] + redS1[2 * ROWS + lw] + redS1[3 * ROWS + lw];
                float q = redQ1[lw] + redQ1[ROWS + lw] + redQ1[2 * ROWS + lw] + redQ1[3 * ROWS + lw];
                float mean = s * 0.0078125f;
                float var  = q * 0.0078125f - mean * mean;
                float rstd = rsqrtf(var + 1e-5f);
#pragma unroll
                for (int n = 0; n < 2; ++n)
                    acc1[m][n][i] = (acc1[m][n][i] - mean) * rstd * gam[n] + bet[n];
            }
    }
    // h2 writes touch smA only; red reads touched smF -> disjoint within phase
#pragma unroll
    for (int m = 0; m < 3; ++m)
#pragma unroll
        for (int i = 0; i < 4; ++i) {
            int rw = lrow[m][i];
#pragma unroll
            for (int n = 0; n < 2; ++n)
                *(unsigned short*)(smA + rw * 256 + ((gcol[n] * 2) ^ ((rw & 7) << 4))) = f2bu(acc1[m][n][i]);
        }
    stage_w<256, 128>(smW, Wf1, t);
    __syncthreads();                                           // B3

    // ---- P4: GEMM2 full: ffmid = relu(h2 @ Wf1^T + bf1), 96x256 ----
    {
        f4 acc2[3][4];
#pragma unroll
        for (int m = 0; m < 3; ++m)
#pragma unroll
            for (int n = 0; n < 4; ++n) acc2[m][n] = (f4){0,0,0,0};
        mm2<3, 4, 4>(smA, 256, smW, 256, wr, wc, lr, lk, acc2);
        int gc2[4];
        float b_[4];
#pragma unroll
        for (int n = 0; n < 4; ++n) { gc2[n] = wc * 64 + n * 16 + lr; b_[n] = bf1[gc2[n]]; }
#pragma unroll
        for (int m = 0; m < 3; ++m)
#pragma unroll
            for (int i = 0; i < 4; ++i) {
                int rw = lrow[m][i];
#pragma unroll
                for (int n = 0; n < 4; ++n) {
                    float v = fmaxf(acc2[m][n][i] + b_[n], 0.f);
                    *(unsigned short*)(smF + rw * 512 + ((gc2[n] * 2) ^ ((rw & 7) << 4))) = f2bu(v);
                }
            }
    }
    __syncthreads();                                           // B4

    // ---- P5: stage Wf2 WHOLE (128x256, 64K) ----
    stage_w<128, 256>(smW, Wf2, t);
    __syncthreads();                                           // B5

    // ---- P6: GEMM3 (K=256) + bf2 + h2(reg) residual + LN2 stats (smA dead) ----
    f4 acc3[3][2];
#pragma unroll
    for (int m = 0; m < 3; ++m) { acc3[m][0] = (f4){0,0,0,0}; acc3[m][1] = (f4){0,0,0,0}; }
    mm2<3, 2, 8>(smF, 512, smW, 512, wr, wc, lr, lk, acc3);
    {
        float b_[2] = { bf2[gcol[0]], bf2[gcol[1]] };
#pragma unroll
        for (int m = 0; m < 3; ++m)
#pragma unroll
            for (int i = 0; i < 4; ++i)
#pragma unroll
                for (int n = 0; n < 2; ++n)
                    acc3[m][n][i] += b_[n] + acc1[m][n][i];
    }
#pragma unroll
    for (int m = 0; m < 3; ++m)
#pragma unroll
        for (int i = 0; i < 4; ++i) {
            float s = acc3[m][0][i] + acc3[m][1][i];
            float q = acc3[m][0][i] * acc3[m][0][i] + acc3[m][1][i] * acc3[m][1][i];
            s += __shfl_xor(s, 1); s += __shfl_xor(s, 2); s += __shfl_xor(s, 4); s += __shfl_xor(s, 8);
            q += __shfl_xor(q, 1); q += __shfl_xor(q, 2); q += __shfl_xor(q, 4); q += __shfl_xor(q, 8);
            if (lr == 0) { redS2[wc * ROWS + lrow[m][i]] = s; redQ2[wc * ROWS + lrow[m][i]] = q; }
        }
    __syncthreads();                                           // B6

    // ---- P7: LN2 finalize; global h stores (keep h_new in regs) ----
    {
        float gam[2] = { g2v[gcol[0]], g2v[gcol[1]] };
        float bet[2] = { b2v[gcol[0]], b2v[gcol[1]] };
#pragma unroll
        for (int m = 0; m < 3; ++m)
#pragma unroll
            for (int i = 0; i < 4; ++i) {
                int lw = lrow[m][i];
                float s = redS2[lw] + redS2[ROWS + lw] + redS2[2 * ROWS + lw] + redS2[3 * ROWS + lw];
                float q = redQ2[lw] + redQ2[ROWS + lw] + redQ2[2 * ROWS + lw] + redQ2[3 * ROWS + lw];
                float mean = s * 0.0078125f;
                float var  = q * 0.0078125f - mean * mean;
                float rstd = rsqrtf(var + 1e-5f);
                int row = n0 + lw;
#pragma unroll
                for (int n = 0; n < 2; ++n) {
                    float o = (acc3[m][n][i] - mean) * rstd * gam[n] + bet[n];
                    acc3[m][n][i] = o;
                    if (row < NN) {
                        hres[(size_t)row * DM + gcol[n]] = __float2bfloat16(o);
                        if (hout_f) hout_f[(size_t)row * DM + gcol[n]] = o;
                    }
                }
            }
    }
    if (!doQKV) return;
    __syncthreads();                                           // B7 (red2 read done)

    // ---- P8: h_new -> smA; stage Wq ----
#pragma unroll
    for (int m = 0; m < 3; ++m)
#pragma unroll
        for (int i = 0; i < 4; ++i) {
            int rw = lrow[m][i];
#pragma unroll
            for (int n = 0; n < 2; ++n)
                *(unsigned short*)(smA + rw * 256 + ((gcol[n] * 2) ^ ((rw & 7) << 4))) = f2bu(acc3[m][n][i]);
        }
    stage_w<128, 128>(smW, Wq, t);
    __syncthreads();                                           // B8

    // ---- P9: GEMM_Q; stage Wk -> smF (ffmid dead) ----
    {
        f4 aq[3][2];
#pragma unroll
        for (int m = 0; m < 3; ++m) { aq[m][0] = (f4){0,0,0,0}; aq[m][1] = (f4){0,0,0,0}; }
        mm2<3, 2, 4>(smA, 256, smW, 256, wr, wc, lr, lk, aq);
        float b_[2] = { bqv[gcol[0]], bqv[gcol[1]] };
#pragma unroll
        for (int m = 0; m < 3; ++m)
#pragma unroll
            for (int i = 0; i < 4; ++i) {
                int row = n0 + lrow[m][i];
                if (row < NN)
#pragma unroll
                    for (int n = 0; n < 2; ++n)
                        Qo[(size_t)row * DM + gcol[n]] = __float2bfloat16(aq[m][n][i] + b_[n]);
            }
    }
    stage_w<128, 128>(smF, Wk, t);
    __syncthreads();                                           // B9

    // ---- P10: GEMM_K (W in smF); stage Wv -> smW ----
    {
        f4 aq[3][2];
#pragma unroll
        for (int m = 0; m < 3; ++m) { aq[m][0] = (f4){0,0,0,0}; aq[m][1] = (f4){0,0,0,0}; }
        mm2<3, 2, 4>(smA, 256, smF, 256, wr, wc, lr, lk, aq);
        float b_[2] = { bkv[gcol[0]], bkv[gcol[1]] };
#pragma unroll
        for (int m = 0; m < 3; ++m)
#pragma unroll
            for (int i = 0; i < 4; ++i) {
                int row = n0 + lrow[m][i];
                if (row < NN)
#pragma unroll
                    for (int n = 0; n < 2; ++n)
                        Ko[(size_t)row * DM + gcol[n]] = __float2bfloat16(aq[m][n][i] + b_[n]);
            }
    }
    stage_w<128, 128>(smW, Wv, t);
    __syncthreads();                                           // B10

    // ---- P11: GEMM_V ----
    {
        f4 aq[3][2];
#pragma unroll
        for (int m = 0; m < 3; ++m) { aq[m][0] = (f4){0,0,0,0}; aq[m][1] = (f4){0,0,0,0}; }
        mm2<3, 2, 4>(smA, 256, smW, 256, wr, wc, lr, lk, aq);
        float b_[2] = { bvv[gcol[0]], bvv[gcol[1]] };
#pragma unroll
        for (int m = 0; m < 3; ++m)
#pragma unroll
            for (int i = 0; i < 4; ++i) {
                int row = n0 + lrow[m][i];
                if (row < NN)
#pragma unroll
                    for (int n = 0; n < 2; ++n)
                        Vo[(size_t)row * DM + gcol[n]] = __float2bfloat16(aq[m][n][i] + b_[n]);
            }
    }
}

// ---------------- edge attention: one wave per dst, 16 lanes per edge ----------------
__global__ __launch_bounds__(256)
void attn_k(const bf16* __restrict__ Q, const bf16* __restrict__ K,
            const bf16* __restrict__ V, const int* __restrict__ row_ptr,
            const int* __restrict__ csr, bf16* __restrict__ out)
{
    int lane = threadIdx.x & 63;
    int n = blockIdx.x * 4 + (threadIdx.x >> 6);
    int g = lane >> 4, sub = lane & 15;
    const uint4* Q4 = (const uint4*)Q;
    const uint4* K4 = (const uint4*)K;
    const uint4* V4 = (const uint4*)V;
    float q[8];
    up8(Q4[n * 16 + sub], q);
    int e0 = row_ptr[n], e1 = row_ptr[n + 1];
    float acc[8] = {0.f, 0.f, 0.f, 0.f, 0.f, 0.f, 0.f, 0.f};
    float zacc = 0.f;

    int e = e0 + g;
    int s0 = (e < e1) ? csr[e] : 0;
    uint4 k0 = K4[(size_t)s0 * 16 + sub];
    uint4 v0 = V4[(size_t)s0 * 16 + sub];
    for (int base = e0; base < e1; base += 4) {
        int en = base + 4 + g;
        int s1 = (en < e1) ? csr[en] : 0;
        uint4 k1 = K4[(size_t)s1 * 16 + sub];
        uint4 v1 = V4[(size_t)s1 * 16 + sub];
        float kf[8];
        up8(k0, kf);
        float p = q[0] * kf[0] + q[1] * kf[1] + q[2] * kf[2] + q[3] * kf[3]
                + q[4] * kf[4] + q[5] * kf[5] + q[6] * kf[6] + q[7] * kf[7];
        p += __shfl_xor(p, 1);
        float sc = __expf(fminf(fmaxf(p * 0.25f, -10.f), 10.f)) * 0.5f;
        if (base + g >= e1) sc = 0.f;
        float vf[8];
        up8(v0, vf);
#pragma unroll
        for (int j = 0; j < 8; ++j) acc[j] = fmaf(sc, vf[j], acc[j]);
        zacc += sc;
        k0 = k1; v0 = v1;
    }
#pragma unroll
    for (int j = 0; j < 8; ++j) {
        acc[j] += __shfl_xor(acc[j], 16);
        acc[j] += __shfl_xor(acc[j], 32);
    }
    zacc += __shfl_xor(zacc, 16);
    zacc += __shfl_xor(zacc, 32);
    float inv = 1.f / (zacc + 1e-6f);
    if (g == 0) {
        uint4 o;
        o.x = pk2(acc[0] * inv, acc[1] * inv);
        o.y = pk2(acc[2] * inv, acc[3] * inv);
        o.z = pk2(acc[4] * inv, acc[5] * inv);
        o.w = pk2(acc[6] * inv, acc[7] * inv);
        ((uint4*)out)[n * 16 + sub] = o;
    }
}

// ---------------- host side ----------------
static inline void g1(hipStream_t st, const bf16* A, const bf16* A2, const bf16* W,
                      const float* bia, float* Cf, bf16* Cb, int N, int K, int M, int post)
{
    dim3 grid((N + 63) / 64, M / 128, 1);
    gemm_k<<<grid, 256, 0, st>>>(A, A2, W, nullptr, nullptr, bia, nullptr, nullptr,
                                 Cf, Cb, nullptr, nullptr, N, K, M, post);
}

static inline void g3(hipStream_t st, const bf16* A,
                      const bf16* W0, const float* b0, bf16* C0,
                      const bf16* W1, const float* b1, bf16* C1,
                      const bf16* W2, const float* b2, bf16* C2,
                      int N, int K, int M)
{
    dim3 grid((N + 63) / 64, M / 128, 3);
    gemm_k<<<grid, 256, 0, st>>>(A, nullptr, W0, W1, W2, b0, b1, b2,
                                 nullptr, C0, C1, C2, N, K, M, 0);
}

extern "C" void kernel_launch(void* const* d_in, const int* in_sizes, int n_in,
                              void* d_out, int out_size, void* d_ws, size_t ws_size,
                              hipStream_t stream)
{
    const float* x    = (const float*)d_in[0];
    const float* Iin  = (const float*)d_in[1];
    const int*   src  = (const int*)d_in[2];
    const int*   dst  = (const int*)d_in[3];
    const float* Wemb = (const float*)d_in[4];
    const float* Wq   = (const float*)d_in[5];  const float* bq  = (const float*)d_in[6];
    const float* Wk   = (const float*)d_in[7];  const float* bk  = (const float*)d_in[8];
    const float* Wv   = (const float*)d_in[9];  const float* bv  = (const float*)d_in[10];
    const float* Wi   = (const float*)d_in[11]; const float* bi  = (const float*)d_in[12];
    const float* Wo   = (const float*)d_in[13]; const float* bo  = (const float*)d_in[14];
    const float* g1g  = (const float*)d_in[15]; const float* be1 = (const float*)d_in[16];
    const float* g2g  = (const float*)d_in[17]; const float* be2 = (const float*)d_in[18];
    const float* Wf1  = (const float*)d_in[19]; const float* bf1 = (const float*)d_in[20];
    const float* Wf2  = (const float*)d_in[21]; const float* bf2 = (const float*)d_in[22];
    const float* Wm1  = (const float*)d_in[23]; const float* bm1 = (const float*)d_in[24];
    const float* Wm2  = (const float*)d_in[25]; const float* bm2 = (const float*)d_in[26];

    const size_t NF = (size_t)NN * DM;          // 2,560,000
    bf16* B      = (bf16*)d_ws;
    bf16* h_b    = B;                           // bf16 residual stream (in-place updated)
    bf16* Qb     = B + NF;
    bf16* Kb     = B + 2 * NF;
    bf16* Vb     = B + 3 * NF;
    bf16* attn_b = B + 4 * NF;
    bf16* Iw_b   = B + 5 * NF;
    bf16* wts    = B + 6 * NF;
    // weight arena offsets (elements)
    bf16* Wemb_b = wts;                 // 32768
    bf16* Wq_b   = wts + 32768;         // 16384
    bf16* Wk_b   = Wq_b + 16384;
    bf16* Wv_b   = Wk_b + 16384;
    bf16* Wo_b   = Wv_b + 16384;
    bf16* Wi_b   = Wo_b + 16384;        // 8192
    bf16* Wf1_b  = Wi_b + 8192;         // 32768
    bf16* Wf2_b  = Wf1_b + 32768;       // 32768
    bf16* Wm1_b  = Wf2_b + 32768;       // 16384
    bf16* Wm2_b  = Wm1_b + 16384;       // 32768
    bf16* wend   = Wm2_b + 32768;
    // aliases over dead regions
    bf16* x_b    = Qb;                  // N x 256 (spans Qb+Kb), dead before QKV0
    bf16* Iin_b  = Vb;                  // N x 64, dead before QKV0
    bf16* tmp_b  = Qb;                  // head mid (N x 128), QKV dead after last layer
    int* ib      = (int*)wend;
    int* cnt     = ib;
    int* cnt2    = ib + NN;
    int* row_ptr = ib + 2 * NN;
    int* csr     = ib + 3 * NN + 1;

    // ---- CSR build (once per call) ----
    hipMemsetAsync(cnt,  0, NN * sizeof(int), stream);
    hipMemsetAsync(cnt2, 0, NN * sizeof(int), stream);
    hist_k<<<(NE + 255) / 256, 256, 0, stream>>>(dst, cnt, NE);
    scan_k<<<1, 1024, 0, stream>>>(cnt, row_ptr, NN);
    scatter_k<<<(NE + 255) / 256, 256, 0, stream>>>(src, dst, row_ptr, cnt2, csr, NE);

    // ---- batched f32->bf16 conversion of x, I, and all weights ----
    Cvt c;
    c.s[0] = x;    c.d[0] = x_b;    c.n[0] = NN * DIN;
    c.s[1] = Iin;  c.d[1] = Iin_b;  c.n[1] = NN * 64;
    c.s[2] = Wemb; c.d[2] = Wemb_b; c.n[2] = 32768;
    c.s[3] = Wq;   c.d[3] = Wq_b;   c.n[3] = 16384;
    c.s[4] = Wk;   c.d[4] = Wk_b;   c.n[4] = 16384;
    c.s[5] = Wv;   c.d[5] = Wv_b;   c.n[5] = 16384;
    c.s[6] = Wo;   c.d[6] = Wo_b;   c.n[6] = 16384;
    c.s[7] = Wi;   c.d[7] = Wi_b;   c.n[7] = 8192;
    c.s[8] = Wf1;  c.d[8] = Wf1_b;  c.n[8] = 32768;
    c.s[9] = Wf2;  c.d[9] = Wf2_b;  c.n[9] = 32768;
    c.s[10] = Wm1; c.d[10] = Wm1_b; c.n[10] = 16384;
    c.s[11] = Wm2; c.d[11] = Wm2_b; c.n[11] = 32768;
    cvt_many_k<<<dim3(640, 12), 256, 0, stream>>>(c);

    // ---- prologue: embed, Iw, first-layer QKV ----
    g1(stream, x_b,   nullptr, Wemb_b, nullptr, nullptr, h_b, NN, DIN, DM, 0);
    g1(stream, Iin_b, nullptr, Wi_b, bi, nullptr, Iw_b, NN, 64, DM, 0);
    g3(stream, h_b, Wq_b, bq, Qb, Wk_b, bk, Kb, Wv_b, bv, Vb, NN, DM, DM);

    // ---- 10 shared-weight layers: attn + mega-fused ----
    const int nblk = (NN + ROWS - 1) / ROWS;    // 209 <= 256 -> single round
    for (int l = 0; l < 10; ++l) {
        attn_k<<<NN / 4, 256, 0, stream>>>(Qb, Kb, Vb, row_ptr, csr, attn_b);
        layer_k<<<nblk, 512, 139264, stream>>>(
            attn_b, Iw_b, h_b, (l == 9) ? (float*)d_out : nullptr,
            Qb, Kb, Vb, (l < 9) ? 1 : 0,
            Wo_b, bo, Wf1_b, bf1, Wf2_b, bf2,
            Wq_b, bq, Wk_b, bk, Wv_b, bv,
            g1g, be1, g2g, be2);
    }

    // ---- reconstruction head ----
    g1(stream, h_b, nullptr, Wm1_b, bm1, nullptr, tmp_b, NN, DM, DM, 2);   // selu
    float* xhat = (float*)d_out + NF;
    g1(stream, tmp_b, nullptr, Wm2_b, bm2, xhat, nullptr, NN, DM, DIN, 0);
}